// Round 3
// baseline (729.686 us; speedup 1.0000x reference)
//
#include <hip/hip_runtime.h>

#define NN 32768
#define NE 524288
#define HD 256

typedef __attribute__((ext_vector_type(8))) __bf16 bf16x8;
typedef __attribute__((ext_vector_type(4))) __bf16 bf16x4;
typedef __attribute__((ext_vector_type(2))) __bf16 bf16x2;
typedef __attribute__((ext_vector_type(4))) float f32x4;

// ---------------- dtype detection ----------------
// Float inputs: fp32 or bf16? Look at low 16 bits of first 64 words of x_ori.
// bf16 data: low half is a bf16 from N(0,1) -> exponent in [90,135].
// fp32 data: low half is mantissa junk -> uniform exponent. P(false) ~ 1e-48.
__global__ __launch_bounds__(64) void k_dtf(const unsigned* __restrict__ w, int* __restrict__ dtflag) {
    int t = threadIdx.x;
    unsigned L = w[t] & 0xFFFFu;
    int e = (int)((L >> 7) & 0xFF);
    unsigned long long b = __ballot(e >= 90 && e <= 135);
    if (t == 0) dtflag[0] = (b == ~0ULL) ? 1 : 0;  // 1 => bf16 inputs
}

// int64 little-endian edges: odd words (high halves) are all 0.
__global__ __launch_bounds__(64) void k_detect(const int* __restrict__ ei, int* __restrict__ eflag) {
    int t = threadIdx.x;
    unsigned long long b = __ballot(ei[2 * t + 1] != 0);
    if (t == 0) eflag[0] = (b == 0ULL) ? 1 : 0;  // 1 => int64 layout
}

// ---------------- conversion ----------------

__device__ __forceinline__ float ld_any(const void* p, int i, int isbf16) {
    return isbf16 ? (float)((const __bf16*)p)[i] : ((const float*)p)[i];
}

struct PtrTable { const void* p[18]; };

#define TOTP 794897

__global__ __launch_bounds__(256) void k_cvt_params(PtrTable pt, const int* __restrict__ dtflag,
                                                    __bf16* __restrict__ blob) {
    const int segoff[19] = {0, 32768, 65536, 65792, 262400, 459008, 459776, 460800, 461824,
                            723968, 724224, 724480, 724481, 724737, 724993, 790529, 790785, 794881, TOTP};
    int i = blockIdx.x * 256 + threadIdx.x;
    if (i >= TOTP) return;
    int s = 0;
    #pragma unroll
    for (int j = 1; j < 18; ++j) s += (i >= segoff[j]) ? 1 : 0;
    blob[i] = (__bf16)ld_any(pt.p[s], i - segoff[s], dtflag[0]);
}

// concat [x_ori|g0|g1|g2] -> X0c [NN,128] bf16
__global__ __launch_bounds__(256) void k_cvt_x0(const void* __restrict__ p0, const void* __restrict__ p1,
                                                const void* __restrict__ p2, const void* __restrict__ p3,
                                                const int* __restrict__ dtflag, __bf16* __restrict__ X0c) {
    int i = blockIdx.x * 256 + threadIdx.x;  // NN*128
    int n = i >> 7, f = i & 127;
    const void* src = (f < 32) ? p0 : (f < 64) ? p1 : (f < 96) ? p2 : p3;
    X0c[i] = (__bf16)ld_any(src, n * 32 + (f & 31), dtflag[0]);
}

// ---------------- CSR build ----------------

__global__ __launch_bounds__(256) void k_deg(const int* __restrict__ ei, const int* __restrict__ eflag,
                                             int* __restrict__ deg) {
    int e = blockIdx.x * 256 + threadIdx.x;
    int d = eflag[0] ? ei[2 * e] : ei[e];
    atomicAdd(&deg[d], 1);
}

__global__ __launch_bounds__(1024) void k_scan(const int* __restrict__ deg, int* __restrict__ offs,
                                               float* __restrict__ invd) {
    __shared__ int wsum[16];
    const int t = threadIdx.x, lane = t & 63, wid = t >> 6;
    const int4* d4 = (const int4*)deg;
    int s = 0;
    #pragma unroll
    for (int j = 0; j < 8; ++j) {
        int4 v = d4[t * 8 + j];
        s += v.x + v.y + v.z + v.w;
    }
    int incl = s;
    #pragma unroll
    for (int d = 1; d < 64; d <<= 1) {
        int y = __shfl_up(incl, d, 64);
        if (lane >= d) incl += y;
    }
    if (lane == 63) wsum[wid] = incl;
    __syncthreads();
    if (t < 16) {
        int v2 = wsum[t];
        int inc2 = v2;
        #pragma unroll
        for (int d = 1; d < 16; d <<= 1) {
            int y = __shfl_up(inc2, d, 64);
            if (t >= d) inc2 += y;
        }
        wsum[t] = inc2 - v2;  // exclusive over wave totals
    }
    __syncthreads();
    int run = (incl - s) + wsum[wid];
    #pragma unroll
    for (int j = 0; j < 8; ++j) {
        int4 v = d4[t * 8 + j];
        int base = t * 32 + j * 4;
        offs[base + 0] = run; invd[base + 0] = v.x ? 1.f / (float)v.x : 0.f; run += v.x;
        offs[base + 1] = run; invd[base + 1] = v.y ? 1.f / (float)v.y : 0.f; run += v.y;
        offs[base + 2] = run; invd[base + 2] = v.z ? 1.f / (float)v.z : 0.f; run += v.z;
        offs[base + 3] = run; invd[base + 3] = v.w ? 1.f / (float)v.w : 0.f; run += v.w;
    }
    if (t == 1023) offs[NN] = run;
}

__global__ __launch_bounds__(256) void k_fill(const int* __restrict__ ei, const int* __restrict__ eflag,
                                              const int* __restrict__ offs, int* __restrict__ cursor,
                                              int* __restrict__ csr) {
    int e = blockIdx.x * 256 + threadIdx.x;
    int f = eflag[0];
    int d = f ? ei[2 * e] : ei[e];
    int s = f ? ei[2 * NE + 2 * e] : ei[NE + e];
    int p = atomicAdd(&cursor[d], 1);
    csr[offs[d] + p] = s;
}

// ---------------- mean aggregation (1 wave per node, 4 nodes/block) ----------------

__global__ __launch_bounds__(256) void k_agg0(const __bf16* __restrict__ X, const int* __restrict__ csr,
                                              const int* __restrict__ offs, const float* __restrict__ invd,
                                              __bf16* __restrict__ M) {
    const int lane = threadIdx.x & 63;
    const int n = blockIdx.x * 4 + (threadIdx.x >> 6);
    const int beg = offs[n], end = offs[n + 1];
    float a0 = 0.f, a1 = 0.f;
    for (int e = beg; e < end; ++e) {
        int s = csr[e];
        bf16x2 v = *(const bf16x2*)&X[(size_t)s * 128 + lane * 2];
        a0 += (float)v[0]; a1 += (float)v[1];
    }
    const float id = invd[n];
    bf16x2 o; o[0] = (__bf16)(a0 * id); o[1] = (__bf16)(a1 * id);
    *(bf16x2*)&M[(size_t)n * 128 + lane * 2] = o;
}

__global__ __launch_bounds__(256) void k_agg(const __bf16* __restrict__ X, const int* __restrict__ csr,
                                             const int* __restrict__ offs, const float* __restrict__ invd,
                                             __bf16* __restrict__ M) {
    const int lane = threadIdx.x & 63;
    const int n = blockIdx.x * 4 + (threadIdx.x >> 6);
    const int beg = offs[n], end = offs[n + 1];
    float a0 = 0.f, a1 = 0.f, a2 = 0.f, a3 = 0.f;
    for (int e = beg; e < end; ++e) {
        int s = csr[e];
        bf16x4 v = *(const bf16x4*)&X[(size_t)s * HD + lane * 4];
        a0 += (float)v[0]; a1 += (float)v[1]; a2 += (float)v[2]; a3 += (float)v[3];
    }
    const float id = invd[n];
    bf16x4 o;
    o[0] = (__bf16)(a0 * id); o[1] = (__bf16)(a1 * id);
    o[2] = (__bf16)(a2 * id); o[3] = (__bf16)(a3 * id);
    *(bf16x4*)&M[(size_t)n * HD + lane * 4] = o;
}

// ---------------- MFMA GEMM: O = A1@W1 (+ A2@W2) + bias ----------------
// 64x64 tile, 4 waves, mfma_f32_16x16x32_bf16.
// STATS: O = bf16(y) + fp32 column sum/sumsq atomics.  !STATS: O = bf16(relu(y)).

template <bool STATS>
__global__ __launch_bounds__(256) void k_gemm(const __bf16* __restrict__ A1, const __bf16* __restrict__ W1,
                                              const __bf16* __restrict__ A2, const __bf16* __restrict__ W2,
                                              const __bf16* __restrict__ bias, int KD,
                                              __bf16* __restrict__ O, float* __restrict__ colsum,
                                              float* __restrict__ colsumsq) {
    __shared__ __bf16 As[64][40];  // [row][k], padded
    __shared__ __bf16 Bs[64][40];  // [col][k] (W transposed during staging)
    const int t = threadIdx.x;
    const int lane = t & 63;
    const int w = t >> 6;
    const int quad = lane >> 4;
    const int l15 = lane & 15;
    const int row0 = blockIdx.x * 64;
    const int c0 = blockIdx.y * 64;
    f32x4 acc[4] = {{0.f, 0.f, 0.f, 0.f}, {0.f, 0.f, 0.f, 0.f}, {0.f, 0.f, 0.f, 0.f}, {0.f, 0.f, 0.f, 0.f}};
    const int ar = t >> 2, ak = (t & 3) * 8;
    const int bc = t & 63, bk = (t >> 6) * 8;
    const int npass = A2 ? 2 : 1;
    for (int pass = 0; pass < npass; ++pass) {
        const __bf16* __restrict__ A = pass ? A2 : A1;
        const __bf16* __restrict__ W = pass ? W2 : W1;
        for (int k0 = 0; k0 < KD; k0 += 32) {
            __syncthreads();
            *(bf16x8*)&As[ar][ak] = *(const bf16x8*)&A[(size_t)(row0 + ar) * KD + (k0 + ak)];
            __bf16 tmp[8];
            #pragma unroll
            for (int j = 0; j < 8; ++j) tmp[j] = W[(size_t)(k0 + bk + j) * HD + (c0 + bc)];
            #pragma unroll
            for (int j = 0; j < 8; ++j) Bs[bc][bk + j] = tmp[j];
            __syncthreads();
            bf16x8 af = *(const bf16x8*)&As[w * 16 + l15][quad * 8];
            #pragma unroll
            for (int n = 0; n < 4; ++n) {
                bf16x8 bfr = *(const bf16x8*)&Bs[n * 16 + l15][quad * 8];
                acc[n] = __builtin_amdgcn_mfma_f32_16x16x32_bf16(af, bfr, acc[n], 0, 0, 0);
            }
        }
    }
    __syncthreads();
    if (STATS) {
        float* lsum = (float*)&As[0][0];
        float* lsq = lsum + 64;
        if (t < 128) lsum[t] = 0.f;
        __syncthreads();
        #pragma unroll
        for (int n = 0; n < 4; ++n) {
            const int col = c0 + n * 16 + l15;
            const float b = (float)bias[col];
            float s = 0.f, q = 0.f;
            #pragma unroll
            for (int r = 0; r < 4; ++r) {
                float y = acc[n][r] + b;
                O[(size_t)(row0 + w * 16 + quad * 4 + r) * HD + col] = (__bf16)y;
                s += y;
                q += y * y;
            }
            s += __shfl_xor(s, 16, 64); s += __shfl_xor(s, 32, 64);
            q += __shfl_xor(q, 16, 64); q += __shfl_xor(q, 32, 64);
            if (quad == 0) {
                atomicAdd(&lsum[n * 16 + l15], s);
                atomicAdd(&lsq[n * 16 + l15], q);
            }
        }
        __syncthreads();
        if (t < 64) atomicAdd(&colsum[c0 + t], lsum[t]);
        else if (t < 128) atomicAdd(&colsumsq[c0 + t - 64], lsq[t - 64]);
    } else {
        #pragma unroll
        for (int n = 0; n < 4; ++n) {
            const int col = c0 + n * 16 + l15;
            const float b = (float)bias[col];
            #pragma unroll
            for (int r = 0; r < 4; ++r) {
                float y = fmaxf(acc[n][r] + b, 0.f);
                O[(size_t)(row0 + w * 16 + quad * 4 + r) * HD + col] = (__bf16)y;
            }
        }
    }
}

// ---------------- BN ----------------

__global__ __launch_bounds__(256) void k_bnparam(const float* __restrict__ colsum, const float* __restrict__ colsumsq,
                                                 const __bf16* __restrict__ gamma, const __bf16* __restrict__ beta,
                                                 float* __restrict__ scale, float* __restrict__ shift, float invn) {
    int c = threadIdx.x;
    float m = colsum[c] * invn;
    float var = fmaxf(colsumsq[c] * invn - m * m, 0.f);
    float rs = rsqrtf(var + 1e-5f);
    float sc = (float)gamma[c] * rs;
    scale[c] = sc;
    shift[c] = (float)beta[c] - m * sc;
}

// in-place: Y (pre-BN bf16) -> relu(BN(Y))
__global__ __launch_bounds__(256) void k_bnapply(__bf16* __restrict__ Y, const float* __restrict__ scale,
                                                 const float* __restrict__ shift) {
    size_t i = (size_t)(blockIdx.x * 256 + threadIdx.x) * 8;
    int c = (int)(i & 255);
    bf16x8 y = *(const bf16x8*)&Y[i];
    bf16x8 o;
    #pragma unroll
    for (int j = 0; j < 8; ++j) o[j] = (__bf16)fmaxf((float)y[j] * scale[c + j] + shift[c + j], 0.f);
    *(bf16x8*)&Y[i] = o;
}

// ---------------- tail ----------------

__global__ __launch_bounds__(256) void k_dot(const __bf16* __restrict__ h, const __bf16* __restrict__ W1b,
                                             const __bf16* __restrict__ b1b, float* __restrict__ x2) {
    const int r = blockIdx.x;
    const int t = threadIdx.x;
    float v = (float)h[(size_t)r * HD + t] * (float)W1b[t];
    #pragma unroll
    for (int d = 1; d < 64; d <<= 1) v += __shfl_xor(v, d, 64);
    __shared__ float ps[4];
    if ((t & 63) == 0) ps[t >> 6] = v;
    __syncthreads();
    if (t == 0) x2[r] = ps[0] + ps[1] + ps[2] + ps[3] + (float)b1b[0];
}

__global__ __launch_bounds__(256) void k_bnf(const float* __restrict__ x2, const __bf16* __restrict__ gf,
                                             const __bf16* __restrict__ bf_, float* __restrict__ x3) {
    int c = threadIdx.x;
    float s = 0.f, q = 0.f;
    for (int b = 0; b < 32; ++b) {
        float v = x2[b * HD + c];
        s += v; q += v * v;
    }
    float m = s * (1.0f / 32.0f);
    float var = fmaxf(q * (1.0f / 32.0f) - m * m, 0.f);
    float rs = rsqrtf(var + 1e-5f);
    float sc = (float)gf[c] * rs;
    float sh = (float)bf_[c] - m * sc;
    for (int b = 0; b < 32; ++b) x3[b * HD + c] = fmaxf(x2[b * HD + c] * sc + sh, 0.f);
}

__global__ __launch_bounds__(256) void k_mlp2a(const float* __restrict__ x3, const __bf16* __restrict__ W2a,
                                               const __bf16* __restrict__ b2a, float* __restrict__ x4) {
    __shared__ float row[HD];
    const int b = blockIdx.x, t = threadIdx.x;
    row[t] = x3[b * HD + t];
    __syncthreads();
    float acc = (float)b2a[t];
    for (int j = 0; j < HD; ++j) acc += row[j] * (float)W2a[j * HD + t];
    x4[b * HD + t] = fmaxf(acc, 0.f);
}

__global__ __launch_bounds__(256) void k_mlp2b(const float* __restrict__ x4, const __bf16* __restrict__ W2b,
                                               const __bf16* __restrict__ b2b, const int* __restrict__ dtflag,
                                               void* __restrict__ out) {
    int t = blockIdx.x * 256 + threadIdx.x;  // 512
    int b = t >> 4, k = t & 15;
    float acc = (float)b2b[k];
    for (int j = 0; j < HD; ++j) acc += x4[b * HD + j] * (float)W2b[j * 16 + k];
    if (dtflag[0]) ((__bf16*)out)[t] = (__bf16)acc;
    else ((float*)out)[t] = acc;
}

// ---------------- launcher ----------------

extern "C" void kernel_launch(void* const* d_in, const int* in_sizes, int n_in,
                              void* d_out, int out_size, void* d_ws, size_t ws_size,
                              hipStream_t stream) {
    const int* ei = (const int*)d_in[4];

    char* ws = (char*)d_ws;
    size_t off_ = 0;
    auto ALLOC = [&](size_t b) { char* p = ws + off_; off_ += (b + 255) & ~(size_t)255; return p; };
    int* dtflag_ = (int*)ALLOC(4);
    int* eflag_ = (int*)ALLOC(4);
    int* deg_ = (int*)ALLOC(NN * 4);
    int* cursor_ = (int*)ALLOC(NN * 4);
    int* offs_ = (int*)ALLOC((NN + 1) * 4);
    float* invd_ = (float*)ALLOC(NN * 4);
    float* colsum_ = (float*)ALLOC(512 * 4);
    float* colsumsq_ = colsum_ + 256;
    float* scale_ = (float*)ALLOC(256 * 4);
    float* shift_ = (float*)ALLOC(256 * 4);
    float* x2_ = (float*)ALLOC(8192 * 4);
    float* x3_ = (float*)ALLOC(32 * 256 * 4);
    float* x4_ = (float*)ALLOC(32 * 256 * 4);
    int* csr_ = (int*)ALLOC((size_t)NE * 4);
    __bf16* blob_ = (__bf16*)ALLOC((size_t)TOTP * 2);
    __bf16* M_ = (__bf16*)ALLOC((size_t)NN * HD * 2);   // reused as h [8192,256]
    __bf16* Xa_ = (__bf16*)ALLOC((size_t)NN * HD * 2);
    __bf16* Xb_ = (__bf16*)ALLOC((size_t)NN * HD * 2);  // first 8MB doubles as X0c
    __bf16* X0c_ = Xb_;   // X0c dead before Xb's first write (layer-1 GEMM output)
    __bf16* h_ = M_;
    // total ~47 MB

    // converted parameter views
    __bf16* Wl0c = blob_ + 0;
    __bf16* Wr0c = blob_ + 32768;
    __bf16* bb0c = blob_ + 65536;
    __bf16* Wlc = blob_ + 65792;
    __bf16* Wrc = blob_ + 262400;
    __bf16* bbc = blob_ + 459008;
    __bf16* gammac = blob_ + 459776;
    __bf16* betac = blob_ + 460800;
    __bf16* W1ac = blob_ + 461824;
    __bf16* b1ac = blob_ + 723968;
    __bf16* W1bc = blob_ + 724224;
    __bf16* b1bc = blob_ + 724480;
    __bf16* gfc = blob_ + 724481;
    __bf16* bfc = blob_ + 724737;
    __bf16* W2ac = blob_ + 724993;
    __bf16* b2ac = blob_ + 790529;
    __bf16* W2bc = blob_ + 790785;
    __bf16* b2bc = blob_ + 794881;

    k_dtf<<<1, 64, 0, stream>>>((const unsigned*)d_in[0], dtflag_);
    k_detect<<<1, 64, 0, stream>>>(ei, eflag_);

    PtrTable pt;
    pt.p[0] = d_in[5];  pt.p[1] = d_in[6];  pt.p[2] = d_in[7];  pt.p[3] = d_in[8];
    pt.p[4] = d_in[9];  pt.p[5] = d_in[10]; pt.p[6] = d_in[11]; pt.p[7] = d_in[12];
    pt.p[8] = d_in[13]; pt.p[9] = d_in[14]; pt.p[10] = d_in[15]; pt.p[11] = d_in[16];
    pt.p[12] = d_in[17]; pt.p[13] = d_in[18]; pt.p[14] = d_in[19]; pt.p[15] = d_in[20];
    pt.p[16] = d_in[21]; pt.p[17] = d_in[22];
    k_cvt_params<<<(TOTP + 255) / 256, 256, 0, stream>>>(pt, dtflag_, blob_);
    k_cvt_x0<<<NN * 128 / 256, 256, 0, stream>>>(d_in[0], d_in[1], d_in[2], d_in[3], dtflag_, X0c_);

    hipMemsetAsync(deg_, 0, NN * 4, stream);
    hipMemsetAsync(cursor_, 0, NN * 4, stream);
    k_deg<<<NE / 256, 256, 0, stream>>>(ei, eflag_, deg_);
    k_scan<<<1, 1024, 0, stream>>>(deg_, offs_, invd_);
    k_fill<<<NE / 256, 256, 0, stream>>>(ei, eflag_, offs_, cursor_, csr_);

    // layer 0 (K=128)
    k_agg0<<<NN / 4, 256, 0, stream>>>(X0c_, csr_, offs_, invd_, M_);
    hipMemsetAsync(colsum_, 0, 512 * 4, stream);
    k_gemm<true><<<dim3(NN / 64, 4), 256, 0, stream>>>(M_, Wl0c, X0c_, Wr0c, bb0c, 128, Xa_, colsum_, colsumsq_);
    k_bnparam<<<1, 256, 0, stream>>>(colsum_, colsumsq_, gammac, betac, scale_, shift_, 1.0f / NN);
    k_bnapply<<<NN / 8, 256, 0, stream>>>(Xa_, scale_, shift_);

    // layers 1..3 (K=256), ping-pong Xa <-> Xb
    __bf16* Xin = Xa_;
    __bf16* Xo = Xb_;
    for (int l = 0; l < 3; ++l) {
        k_agg<<<NN / 4, 256, 0, stream>>>(Xin, csr_, offs_, invd_, M_);
        hipMemsetAsync(colsum_, 0, 512 * 4, stream);
        k_gemm<true><<<dim3(NN / 64, 4), 256, 0, stream>>>(M_, Wlc + (size_t)l * HD * HD, Xin,
                                                           Wrc + (size_t)l * HD * HD, bbc + l * HD, 256, Xo,
                                                           colsum_, colsumsq_);
        k_bnparam<<<1, 256, 0, stream>>>(colsum_, colsumsq_, gammac + (l + 1) * HD, betac + (l + 1) * HD,
                                         scale_, shift_, 1.0f / NN);
        k_bnapply<<<NN / 8, 256, 0, stream>>>(Xo, scale_, shift_);
        __bf16* tmp = Xin; Xin = Xo; Xo = tmp;
    }
    // Xin = layer-3 output, flat-viewed as [8192, 1024]

    // mlp1: h = relu(Xin @ W1a + b1a)
    k_gemm<false><<<dim3(8192 / 64, 4), 256, 0, stream>>>(Xin, W1ac, nullptr, nullptr, b1ac, 1024, h_,
                                                          nullptr, nullptr);
    k_dot<<<8192, 256, 0, stream>>>(h_, W1bc, b1bc, x2_);
    k_bnf<<<1, 256, 0, stream>>>(x2_, gfc, bfc, x3_);
    k_mlp2a<<<32, 256, 0, stream>>>(x3_, W2ac, b2ac, x4_);
    k_mlp2b<<<2, 256, 0, stream>>>(x4_, W2bc, b2bc, dtflag_, d_out);
}

// Round 4
// 561.626 us; speedup vs baseline: 1.2992x; 1.2992x over previous
//
#include <hip/hip_runtime.h>

#define NN 32768
#define NE 524288
#define HD 256
#define TOTP 794897

typedef __attribute__((ext_vector_type(8))) __bf16 bf16x8;
typedef __attribute__((ext_vector_type(4))) __bf16 bf16x4;
typedef __attribute__((ext_vector_type(2))) __bf16 bf16x2;
typedef __attribute__((ext_vector_type(4))) float f32x4;

// ---------------- dtype detection ----------------
__global__ __launch_bounds__(64) void k_dtf(const unsigned* __restrict__ w, int* __restrict__ dtflag) {
    int t = threadIdx.x;
    unsigned L = w[t] & 0xFFFFu;
    int e = (int)((L >> 7) & 0xFF);
    unsigned long long b = __ballot(e >= 90 && e <= 135);
    if (t == 0) dtflag[0] = (b == ~0ULL) ? 1 : 0;  // 1 => bf16 inputs
}

__global__ __launch_bounds__(64) void k_detect(const int* __restrict__ ei, int* __restrict__ eflag) {
    int t = threadIdx.x;
    unsigned long long b = __ballot(ei[2 * t + 1] != 0);
    if (t == 0) eflag[0] = (b == 0ULL) ? 1 : 0;  // 1 => int64 layout
}

// ---------------- conversion (+ weight transpose) ----------------

__device__ __forceinline__ float ld_any(const void* p, int i, int isbf16) {
    return isbf16 ? (float)((const __bf16*)p)[i] : ((const float*)p)[i];
}

struct PtrTable { const void* p[18]; };

// Segments: GEMM weight matrices are transposed ([R][C] -> [C][R]) so GEMM
// B-staging becomes contiguous 16B vector loads. All dims are powers of 2.
__global__ __launch_bounds__(256) void k_cvt_params(PtrTable pt, const int* __restrict__ dtflag,
                                                    __bf16* __restrict__ blob) {
    const int off[23] = {0, 32768, 65536, 65792, 131328, 196864, 262400, 327936, 393472,
                         459008, 459776, 460800, 461824, 723968, 724224, 724480, 724481,
                         724737, 724993, 790529, 790785, 794881, TOTP};
    const signed char pidx[22] = {0, 1, 2, 3, 3, 3, 4, 4, 4, 5, 6, 7, 8, 9, 10, 11, 12, 13, 14, 15, 16, 17};
    const int sbase[22] = {0, 0, 0, 0, 65536, 131072, 0, 65536, 131072, 0, 0, 0, 0, 0, 0, 0, 0, 0, 0, 0, 0, 0};
    const signed char lR[22] = {7, 7, -1, 8, 8, 8, 8, 8, 8, -1, -1, -1, 10, -1, -1, -1, -1, -1, -1, -1, -1, -1};
    const signed char lC[22] = {8, 8, 0, 8, 8, 8, 8, 8, 8, 0, 0, 0, 8, 0, 0, 0, 0, 0, 0, 0, 0, 0};
    int i = blockIdx.x * 256 + threadIdx.x;
    if (i >= TOTP) return;
    int s = 0;
    while (i >= off[s + 1]) ++s;
    int j = i - off[s];
    int si;
    if (lR[s] >= 0) {
        int Rm = (1 << lR[s]) - 1;
        si = sbase[s] + ((j & Rm) << lC[s]) + (j >> lR[s]);  // transpose read
    } else {
        si = sbase[s] + j;
    }
    blob[i] = (__bf16)ld_any(pt.p[pidx[s]], si, dtflag[0]);
}

__global__ __launch_bounds__(256) void k_cvt_x0(const void* __restrict__ p0, const void* __restrict__ p1,
                                                const void* __restrict__ p2, const void* __restrict__ p3,
                                                const int* __restrict__ dtflag, __bf16* __restrict__ X0c) {
    int i = blockIdx.x * 256 + threadIdx.x;  // NN*128
    int n = i >> 7, f = i & 127;
    const void* src = (f < 32) ? p0 : (f < 64) ? p1 : (f < 96) ? p2 : p3;
    X0c[i] = (__bf16)ld_any(src, n * 32 + (f & 31), dtflag[0]);
}

// ---------------- CSR build ----------------

__global__ __launch_bounds__(256) void k_deg(const int* __restrict__ ei, const int* __restrict__ eflag,
                                             int* __restrict__ deg) {
    int e = blockIdx.x * 256 + threadIdx.x;
    int d = eflag[0] ? ei[2 * e] : ei[e];
    atomicAdd(&deg[d], 1);
}

__global__ __launch_bounds__(1024) void k_scan(const int* __restrict__ deg, int* __restrict__ offs,
                                               float* __restrict__ invd) {
    __shared__ int wsum[16];
    const int t = threadIdx.x, lane = t & 63, wid = t >> 6;
    const int4* d4 = (const int4*)deg;
    int s = 0;
    #pragma unroll
    for (int j = 0; j < 8; ++j) {
        int4 v = d4[t * 8 + j];
        s += v.x + v.y + v.z + v.w;
    }
    int incl = s;
    #pragma unroll
    for (int d = 1; d < 64; d <<= 1) {
        int y = __shfl_up(incl, d, 64);
        if (lane >= d) incl += y;
    }
    if (lane == 63) wsum[wid] = incl;
    __syncthreads();
    if (t < 16) {
        int v2 = wsum[t];
        int inc2 = v2;
        #pragma unroll
        for (int d = 1; d < 16; d <<= 1) {
            int y = __shfl_up(inc2, d, 64);
            if (t >= d) inc2 += y;
        }
        wsum[t] = inc2 - v2;  // exclusive over wave totals
    }
    __syncthreads();
    int run = (incl - s) + wsum[wid];
    #pragma unroll
    for (int j = 0; j < 8; ++j) {
        int4 v = d4[t * 8 + j];
        int base = t * 32 + j * 4;
        offs[base + 0] = run; invd[base + 0] = v.x ? 1.f / (float)v.x : 0.f; run += v.x;
        offs[base + 1] = run; invd[base + 1] = v.y ? 1.f / (float)v.y : 0.f; run += v.y;
        offs[base + 2] = run; invd[base + 2] = v.z ? 1.f / (float)v.z : 0.f; run += v.z;
        offs[base + 3] = run; invd[base + 3] = v.w ? 1.f / (float)v.w : 0.f; run += v.w;
    }
    if (t == 1023) offs[NN] = run;
}

__global__ __launch_bounds__(256) void k_fill(const int* __restrict__ ei, const int* __restrict__ eflag,
                                              const int* __restrict__ offs, int* __restrict__ cursor,
                                              int* __restrict__ csr) {
    int e = blockIdx.x * 256 + threadIdx.x;
    int f = eflag[0];
    int d = f ? ei[2 * e] : ei[e];
    int s = f ? ei[2 * NE + 2 * e] : ei[NE + e];
    int p = atomicAdd(&cursor[d], 1);
    csr[offs[d] + p] = s;
}

// ---------------- mean aggregation ----------------
// 16B lanes + 4x edge unroll => up to 8 independent 512B gathers in flight
// per wave (was 1 dependent stream: VALUBusy 17.6%, 2 TB/s, latency-bound).

__global__ __launch_bounds__(256) void k_agg0(const __bf16* __restrict__ X, const int* __restrict__ csr,
                                              const int* __restrict__ offs, const float* __restrict__ invd,
                                              __bf16* __restrict__ M) {
    const int t = threadIdx.x;
    const int n = blockIdx.x * 16 + (t >> 4);  // 16 lanes per node (128 feats)
    const size_t lo = (size_t)(t & 15) * 8;
    const int beg = offs[n], end = offs[n + 1];
    float a[8] = {0.f, 0.f, 0.f, 0.f, 0.f, 0.f, 0.f, 0.f};
    int e = beg;
    for (; e + 4 <= end; e += 4) {
        int s0 = csr[e], s1 = csr[e + 1], s2 = csr[e + 2], s3 = csr[e + 3];
        bf16x8 v0 = *(const bf16x8*)&X[(size_t)s0 * 128 + lo];
        bf16x8 v1 = *(const bf16x8*)&X[(size_t)s1 * 128 + lo];
        bf16x8 v2 = *(const bf16x8*)&X[(size_t)s2 * 128 + lo];
        bf16x8 v3 = *(const bf16x8*)&X[(size_t)s3 * 128 + lo];
        #pragma unroll
        for (int j = 0; j < 8; ++j) a[j] += (float)v0[j] + (float)v1[j] + (float)v2[j] + (float)v3[j];
    }
    for (; e < end; ++e) {
        bf16x8 v = *(const bf16x8*)&X[(size_t)csr[e] * 128 + lo];
        #pragma unroll
        for (int j = 0; j < 8; ++j) a[j] += (float)v[j];
    }
    const float id = invd[n];
    bf16x8 o;
    #pragma unroll
    for (int j = 0; j < 8; ++j) o[j] = (__bf16)(a[j] * id);
    *(bf16x8*)&M[(size_t)n * 128 + lo] = o;
}

__global__ __launch_bounds__(256) void k_agg(const __bf16* __restrict__ X, const int* __restrict__ csr,
                                             const int* __restrict__ offs, const float* __restrict__ invd,
                                             __bf16* __restrict__ M) {
    const int t = threadIdx.x;
    const int n = blockIdx.x * 8 + (t >> 5);  // 32 lanes per node (256 feats)
    const size_t lo = (size_t)(t & 31) * 8;
    const int beg = offs[n], end = offs[n + 1];
    float a[8] = {0.f, 0.f, 0.f, 0.f, 0.f, 0.f, 0.f, 0.f};
    int e = beg;
    for (; e + 4 <= end; e += 4) {
        int s0 = csr[e], s1 = csr[e + 1], s2 = csr[e + 2], s3 = csr[e + 3];
        bf16x8 v0 = *(const bf16x8*)&X[(size_t)s0 * HD + lo];
        bf16x8 v1 = *(const bf16x8*)&X[(size_t)s1 * HD + lo];
        bf16x8 v2 = *(const bf16x8*)&X[(size_t)s2 * HD + lo];
        bf16x8 v3 = *(const bf16x8*)&X[(size_t)s3 * HD + lo];
        #pragma unroll
        for (int j = 0; j < 8; ++j) a[j] += (float)v0[j] + (float)v1[j] + (float)v2[j] + (float)v3[j];
    }
    for (; e < end; ++e) {
        bf16x8 v = *(const bf16x8*)&X[(size_t)csr[e] * HD + lo];
        #pragma unroll
        for (int j = 0; j < 8; ++j) a[j] += (float)v[j];
    }
    const float id = invd[n];
    bf16x8 o;
    #pragma unroll
    for (int j = 0; j < 8; ++j) o[j] = (__bf16)(a[j] * id);
    *(bf16x8*)&M[(size_t)n * HD + lo] = o;
}

// ---------------- MFMA GEMM: O = A1@W1 (+ A2@W2) + bias ----------------
// 128x64 tile, 4 waves x (2 m-tiles x 4 n-tiles) = 32 MFMA per K-step.
// Weights pre-transposed: WT[n][k] => B-staging is bf16x8 vector loads.

template <bool STATS>
__global__ __launch_bounds__(256) void k_gemm(const __bf16* __restrict__ A1, const __bf16* __restrict__ WT1,
                                              const __bf16* __restrict__ A2, const __bf16* __restrict__ WT2,
                                              const __bf16* __restrict__ bias, int KD,
                                              __bf16* __restrict__ O, float* __restrict__ colsum,
                                              float* __restrict__ colsumsq) {
    __shared__ __bf16 As[128][40];  // [row][k], pad 40: 2-way max on ds_read (free)
    __shared__ __bf16 Bs[64][40];   // [col][k]
    const int t = threadIdx.x;
    const int lane = t & 63;
    const int w = t >> 6;
    const int quad = lane >> 4;
    const int l15 = lane & 15;
    const int row0 = blockIdx.x * 128;
    const int c0 = blockIdx.y * 64;
    f32x4 acc[8] = {{0.f,0.f,0.f,0.f},{0.f,0.f,0.f,0.f},{0.f,0.f,0.f,0.f},{0.f,0.f,0.f,0.f},
                    {0.f,0.f,0.f,0.f},{0.f,0.f,0.f,0.f},{0.f,0.f,0.f,0.f},{0.f,0.f,0.f,0.f}};
    const int ar = t >> 1, ak = (t & 1) * 16;  // A: 128 rows x 32 k
    const int bc = t & 63, bk = (t >> 6) * 8;  // B: 64 cols x 32 k
    const int rw = w * 32;
    const int npass = A2 ? 2 : 1;
    for (int pass = 0; pass < npass; ++pass) {
        const __bf16* __restrict__ A = pass ? A2 : A1;
        const __bf16* __restrict__ WT = pass ? WT2 : WT1;
        for (int k0 = 0; k0 < KD; k0 += 32) {
            __syncthreads();
            const __bf16* ap = &A[(size_t)(row0 + ar) * KD + (k0 + ak)];
            *(bf16x8*)&As[ar][ak] = *(const bf16x8*)ap;
            *(bf16x8*)&As[ar][ak + 8] = *(const bf16x8*)(ap + 8);
            *(bf16x8*)&Bs[bc][bk] = *(const bf16x8*)&WT[(size_t)(c0 + bc) * KD + (k0 + bk)];
            __syncthreads();
            bf16x8 af0 = *(const bf16x8*)&As[rw + l15][quad * 8];
            bf16x8 af1 = *(const bf16x8*)&As[rw + 16 + l15][quad * 8];
            #pragma unroll
            for (int n = 0; n < 4; ++n) {
                bf16x8 bfr = *(const bf16x8*)&Bs[n * 16 + l15][quad * 8];
                acc[n] = __builtin_amdgcn_mfma_f32_16x16x32_bf16(af0, bfr, acc[n], 0, 0, 0);
                acc[4 + n] = __builtin_amdgcn_mfma_f32_16x16x32_bf16(af1, bfr, acc[4 + n], 0, 0, 0);
            }
        }
    }
    __syncthreads();
    if (STATS) {
        float* lsum = (float*)&As[0][0];
        float* lsq = lsum + 64;
        if (t < 128) lsum[t] = 0.f;
        __syncthreads();
        #pragma unroll
        for (int n = 0; n < 4; ++n) {
            const int col = c0 + n * 16 + l15;
            const float b = (float)bias[col];
            float s = 0.f, q = 0.f;
            #pragma unroll
            for (int mt = 0; mt < 2; ++mt) {
                #pragma unroll
                for (int r = 0; r < 4; ++r) {
                    float y = acc[mt * 4 + n][r] + b;
                    O[(size_t)(row0 + rw + mt * 16 + quad * 4 + r) * HD + col] = (__bf16)y;
                    s += y;
                    q += y * y;
                }
            }
            s += __shfl_xor(s, 16, 64); s += __shfl_xor(s, 32, 64);
            q += __shfl_xor(q, 16, 64); q += __shfl_xor(q, 32, 64);
            if (quad == 0) {
                atomicAdd(&lsum[n * 16 + l15], s);
                atomicAdd(&lsq[n * 16 + l15], q);
            }
        }
        __syncthreads();
        if (t < 64) atomicAdd(&colsum[c0 + t], lsum[t]);
        else if (t < 128) atomicAdd(&colsumsq[c0 + t - 64], lsq[t - 64]);
    } else {
        #pragma unroll
        for (int n = 0; n < 4; ++n) {
            const int col = c0 + n * 16 + l15;
            const float b = (float)bias[col];
            #pragma unroll
            for (int mt = 0; mt < 2; ++mt) {
                #pragma unroll
                for (int r = 0; r < 4; ++r) {
                    float y = fmaxf(acc[mt * 4 + n][r] + b, 0.f);
                    O[(size_t)(row0 + rw + mt * 16 + quad * 4 + r) * HD + col] = (__bf16)y;
                }
            }
        }
    }
}

// ---------------- BN ----------------

__global__ __launch_bounds__(256) void k_bnparam(const float* __restrict__ colsum, const float* __restrict__ colsumsq,
                                                 const __bf16* __restrict__ gamma, const __bf16* __restrict__ beta,
                                                 float* __restrict__ scale, float* __restrict__ shift, float invn) {
    int c = threadIdx.x;
    float m = colsum[c] * invn;
    float var = fmaxf(colsumsq[c] * invn - m * m, 0.f);
    float rs = rsqrtf(var + 1e-5f);
    float sc = (float)gamma[c] * rs;
    scale[c] = sc;
    shift[c] = (float)beta[c] - m * sc;
}

__global__ __launch_bounds__(256) void k_bnapply(__bf16* __restrict__ Y, const float* __restrict__ scale,
                                                 const float* __restrict__ shift) {
    size_t i = (size_t)(blockIdx.x * 256 + threadIdx.x) * 8;
    int c = (int)(i & 255);
    bf16x8 y = *(const bf16x8*)&Y[i];
    bf16x8 o;
    #pragma unroll
    for (int j = 0; j < 8; ++j) o[j] = (__bf16)fmaxf((float)y[j] * scale[c + j] + shift[c + j], 0.f);
    *(bf16x8*)&Y[i] = o;
}

// ---------------- tail ----------------

__global__ __launch_bounds__(256) void k_dot(const __bf16* __restrict__ h, const __bf16* __restrict__ W1b,
                                             const __bf16* __restrict__ b1b, float* __restrict__ x2) {
    const int r = blockIdx.x;
    const int t = threadIdx.x;
    float v = (float)h[(size_t)r * HD + t] * (float)W1b[t];
    #pragma unroll
    for (int d = 1; d < 64; d <<= 1) v += __shfl_xor(v, d, 64);
    __shared__ float ps[4];
    if ((t & 63) == 0) ps[t >> 6] = v;
    __syncthreads();
    if (t == 0) x2[r] = ps[0] + ps[1] + ps[2] + ps[3] + (float)b1b[0];
}

__global__ __launch_bounds__(256) void k_bnf(const float* __restrict__ x2, const __bf16* __restrict__ gf,
                                             const __bf16* __restrict__ bf_, float* __restrict__ x3) {
    int c = threadIdx.x;
    float s = 0.f, q = 0.f;
    for (int b = 0; b < 32; ++b) {
        float v = x2[b * HD + c];
        s += v; q += v * v;
    }
    float m = s * (1.0f / 32.0f);
    float var = fmaxf(q * (1.0f / 32.0f) - m * m, 0.f);
    float rs = rsqrtf(var + 1e-5f);
    float sc = (float)gf[c] * rs;
    float sh = (float)bf_[c] - m * sc;
    for (int b = 0; b < 32; ++b) x3[b * HD + c] = fmaxf(x2[b * HD + c] * sc + sh, 0.f);
}

__global__ __launch_bounds__(256) void k_mlp2a(const float* __restrict__ x3, const __bf16* __restrict__ W2a,
                                               const __bf16* __restrict__ b2a, float* __restrict__ x4) {
    __shared__ float row[HD];
    const int b = blockIdx.x, t = threadIdx.x;
    row[t] = x3[b * HD + t];
    __syncthreads();
    float acc = (float)b2a[t];
    for (int j = 0; j < HD; ++j) acc += row[j] * (float)W2a[j * HD + t];
    x4[b * HD + t] = fmaxf(acc, 0.f);
}

__global__ __launch_bounds__(256) void k_mlp2b(const float* __restrict__ x4, const __bf16* __restrict__ W2b,
                                               const __bf16* __restrict__ b2b, const int* __restrict__ dtflag,
                                               void* __restrict__ out) {
    int t = blockIdx.x * 256 + threadIdx.x;  // 512
    int b = t >> 4, k = t & 15;
    float acc = (float)b2b[k];
    for (int j = 0; j < HD; ++j) acc += x4[b * HD + j] * (float)W2b[j * 16 + k];
    if (dtflag[0]) ((__bf16*)out)[t] = (__bf16)acc;
    else ((float*)out)[t] = acc;
}

// ---------------- launcher ----------------

extern "C" void kernel_launch(void* const* d_in, const int* in_sizes, int n_in,
                              void* d_out, int out_size, void* d_ws, size_t ws_size,
                              hipStream_t stream) {
    const int* ei = (const int*)d_in[4];

    char* ws = (char*)d_ws;
    size_t off_ = 0;
    auto ALLOC = [&](size_t b) { char* p = ws + off_; off_ += (b + 255) & ~(size_t)255; return p; };
    int* dtflag_ = (int*)ALLOC(4);
    int* eflag_ = (int*)ALLOC(4);
    int* deg_ = (int*)ALLOC(NN * 4);
    int* cursor_ = (int*)ALLOC(NN * 4);
    int* offs_ = (int*)ALLOC((NN + 1) * 4);
    float* invd_ = (float*)ALLOC(NN * 4);
    float* colsum_ = (float*)ALLOC(512 * 4);
    float* colsumsq_ = colsum_ + 256;
    float* scale_ = (float*)ALLOC(256 * 4);
    float* shift_ = (float*)ALLOC(256 * 4);
    float* x2_ = (float*)ALLOC(8192 * 4);
    float* x3_ = (float*)ALLOC(32 * 256 * 4);
    float* x4_ = (float*)ALLOC(32 * 256 * 4);
    int* csr_ = (int*)ALLOC((size_t)NE * 4);
    __bf16* blob_ = (__bf16*)ALLOC((size_t)TOTP * 2);
    __bf16* M_ = (__bf16*)ALLOC((size_t)NN * HD * 2);   // reused as h [8192,256]
    __bf16* Xa_ = (__bf16*)ALLOC((size_t)NN * HD * 2);
    __bf16* Xb_ = (__bf16*)ALLOC((size_t)NN * HD * 2);  // first 8MB doubles as X0c
    __bf16* X0c_ = Xb_;  // dead before layer-1 GEMM writes Xb
    __bf16* h_ = M_;

    // converted parameter views (weight matrices transposed)
    __bf16* Wl0T = blob_ + 0;
    __bf16* Wr0T = blob_ + 32768;
    __bf16* bb0c = blob_ + 65536;
    __bf16* WlT = blob_ + 65792;     // 3 x [256][256]
    __bf16* WrT = blob_ + 262400;
    __bf16* bbc = blob_ + 459008;
    __bf16* gammac = blob_ + 459776;
    __bf16* betac = blob_ + 460800;
    __bf16* W1aT = blob_ + 461824;   // [256][1024]
    __bf16* b1ac = blob_ + 723968;
    __bf16* W1bc = blob_ + 724224;
    __bf16* b1bc = blob_ + 724480;
    __bf16* gfc = blob_ + 724481;
    __bf16* bfc = blob_ + 724737;
    __bf16* W2ac = blob_ + 724993;   // untransposed (tiny kernel wants k-major)
    __bf16* b2ac = blob_ + 790529;
    __bf16* W2bc = blob_ + 790785;
    __bf16* b2bc = blob_ + 794881;

    k_dtf<<<1, 64, 0, stream>>>((const unsigned*)d_in[0], dtflag_);
    k_detect<<<1, 64, 0, stream>>>(ei, eflag_);

    PtrTable pt;
    pt.p[0] = d_in[5];  pt.p[1] = d_in[6];  pt.p[2] = d_in[7];  pt.p[3] = d_in[8];
    pt.p[4] = d_in[9];  pt.p[5] = d_in[10]; pt.p[6] = d_in[11]; pt.p[7] = d_in[12];
    pt.p[8] = d_in[13]; pt.p[9] = d_in[14]; pt.p[10] = d_in[15]; pt.p[11] = d_in[16];
    pt.p[12] = d_in[17]; pt.p[13] = d_in[18]; pt.p[14] = d_in[19]; pt.p[15] = d_in[20];
    pt.p[16] = d_in[21]; pt.p[17] = d_in[22];
    k_cvt_params<<<(TOTP + 255) / 256, 256, 0, stream>>>(pt, dtflag_, blob_);
    k_cvt_x0<<<NN * 128 / 256, 256, 0, stream>>>(d_in[0], d_in[1], d_in[2], d_in[3], dtflag_, X0c_);

    hipMemsetAsync(deg_, 0, NN * 4, stream);
    hipMemsetAsync(cursor_, 0, NN * 4, stream);
    k_deg<<<NE / 256, 256, 0, stream>>>(ei, eflag_, deg_);
    k_scan<<<1, 1024, 0, stream>>>(deg_, offs_, invd_);
    k_fill<<<NE / 256, 256, 0, stream>>>(ei, eflag_, offs_, cursor_, csr_);

    // layer 0 (K=128)
    k_agg0<<<NN / 16, 256, 0, stream>>>(X0c_, csr_, offs_, invd_, M_);
    hipMemsetAsync(colsum_, 0, 512 * 4, stream);
    k_gemm<true><<<dim3(NN / 128, 4), 256, 0, stream>>>(M_, Wl0T, X0c_, Wr0T, bb0c, 128, Xa_, colsum_, colsumsq_);
    k_bnparam<<<1, 256, 0, stream>>>(colsum_, colsumsq_, gammac, betac, scale_, shift_, 1.0f / NN);
    k_bnapply<<<NN / 8, 256, 0, stream>>>(Xa_, scale_, shift_);

    // layers 1..3 (K=256), ping-pong Xa <-> Xb
    __bf16* Xin = Xa_;
    __bf16* Xo = Xb_;
    for (int l = 0; l < 3; ++l) {
        k_agg<<<NN / 8, 256, 0, stream>>>(Xin, csr_, offs_, invd_, M_);
        hipMemsetAsync(colsum_, 0, 512 * 4, stream);
        k_gemm<true><<<dim3(NN / 128, 4), 256, 0, stream>>>(M_, WlT + (size_t)l * HD * HD, Xin,
                                                            WrT + (size_t)l * HD * HD, bbc + l * HD, 256, Xo,
                                                            colsum_, colsumsq_);
        k_bnparam<<<1, 256, 0, stream>>>(colsum_, colsumsq_, gammac + (l + 1) * HD, betac + (l + 1) * HD,
                                         scale_, shift_, 1.0f / NN);
        k_bnapply<<<NN / 8, 256, 0, stream>>>(Xo, scale_, shift_);
        __bf16* tmp = Xin; Xin = Xo; Xo = tmp;
    }
    // Xin = layer-3 output, flat-viewed as [8192, 1024]

    // mlp1: h = relu(Xin @ W1a + b1a)
    k_gemm<false><<<dim3(8192 / 128, 4), 256, 0, stream>>>(Xin, W1aT, nullptr, nullptr, b1ac, 1024, h_,
                                                           nullptr, nullptr);
    k_dot<<<8192, 256, 0, stream>>>(h_, W1bc, b1bc, x2_);
    k_bnf<<<1, 256, 0, stream>>>(x2_, gfc, bfc, x3_);
    k_mlp2a<<<32, 256, 0, stream>>>(x3_, W2ac, b2ac, x4_);
    k_mlp2b<<<2, 256, 0, stream>>>(x4_, W2bc, b2bc, dtflag_, d_out);
}

// Round 5
// 556.197 us; speedup vs baseline: 1.3119x; 1.0098x over previous
//
#include <hip/hip_runtime.h>

#define NN 32768
#define NE 524288
#define HD 256
#define TOTP 794897

typedef __attribute__((ext_vector_type(8))) __bf16 bf16x8;
typedef __attribute__((ext_vector_type(4))) __bf16 bf16x4;
typedef __attribute__((ext_vector_type(4))) float f32x4;

// ---------------- detection (dtype of floats, layout of edge_index) ----------------
__global__ __launch_bounds__(128) void k_det(const unsigned* __restrict__ x, const int* __restrict__ ei,
                                             int* __restrict__ flags) {
    int t = threadIdx.x;
    if (t < 64) {
        unsigned L = x[t] & 0xFFFFu;
        int e = (int)((L >> 7) & 0xFF);
        unsigned long long b = __ballot(e >= 90 && e <= 135);
        if (t == 0) flags[0] = (b == ~0ULL) ? 1 : 0;  // 1 => bf16 inputs
    } else {
        int u = t - 64;
        unsigned long long b = __ballot(ei[2 * u + 1] != 0);
        if (t == 64) flags[1] = (b == 0ULL) ? 1 : 0;  // 1 => int64 edges
    }
}

// ---------------- conversion (+ weight transpose) ----------------

__device__ __forceinline__ float ld_any(const void* p, int i, int isbf16) {
    return isbf16 ? (float)((const __bf16*)p)[i] : ((const float*)p)[i];
}

struct PtrTable { const void* p[18]; };

__global__ __launch_bounds__(256) void k_cvt_params(PtrTable pt, const int* __restrict__ flags,
                                                    __bf16* __restrict__ blob) {
    const int off[23] = {0, 32768, 65536, 65792, 131328, 196864, 262400, 327936, 393472,
                         459008, 459776, 460800, 461824, 723968, 724224, 724480, 724481,
                         724737, 724993, 790529, 790785, 794881, TOTP};
    const signed char pidx[22] = {0, 1, 2, 3, 3, 3, 4, 4, 4, 5, 6, 7, 8, 9, 10, 11, 12, 13, 14, 15, 16, 17};
    const int sbase[22] = {0, 0, 0, 0, 65536, 131072, 0, 65536, 131072, 0, 0, 0, 0, 0, 0, 0, 0, 0, 0, 0, 0, 0};
    const signed char lR[22] = {7, 7, -1, 8, 8, 8, 8, 8, 8, -1, -1, -1, 10, -1, -1, -1, -1, -1, -1, -1, -1, -1};
    const signed char lC[22] = {8, 8, 0, 8, 8, 8, 8, 8, 8, 0, 0, 0, 8, 0, 0, 0, 0, 0, 0, 0, 0, 0};
    int i = blockIdx.x * 256 + threadIdx.x;
    if (i >= TOTP) return;
    int s = 0;
    while (i >= off[s + 1]) ++s;
    int j = i - off[s];
    int si;
    if (lR[s] >= 0) {
        int Rm = (1 << lR[s]) - 1;
        si = sbase[s] + ((j & Rm) << lC[s]) + (j >> lR[s]);  // transpose read
    } else {
        si = sbase[s] + j;
    }
    blob[i] = (__bf16)ld_any(pt.p[pidx[s]], si, flags[0]);
}

__global__ __launch_bounds__(256) void k_cvt_x0(const void* __restrict__ p0, const void* __restrict__ p1,
                                                const void* __restrict__ p2, const void* __restrict__ p3,
                                                const int* __restrict__ flags, __bf16* __restrict__ X0c) {
    int i = blockIdx.x * 256 + threadIdx.x;  // NN*128
    int n = i >> 7, f = i & 127;
    const void* src = (f < 32) ? p0 : (f < 64) ? p1 : (f < 96) ? p2 : p3;
    X0c[i] = (__bf16)ld_any(src, n * 32 + (f & 31), flags[0]);
}

// ---------------- CSR build ----------------

__global__ __launch_bounds__(256) void k_deg(const int* __restrict__ ei, const int* __restrict__ flags,
                                             int* __restrict__ deg) {
    int e = blockIdx.x * 256 + threadIdx.x;
    int d = flags[1] ? ei[2 * e] : ei[e];
    atomicAdd(&deg[d], 1);
}

__global__ __launch_bounds__(1024) void k_scan(const int* __restrict__ deg, int* __restrict__ offs,
                                               float* __restrict__ invd) {
    __shared__ int wsum[16];
    const int t = threadIdx.x, lane = t & 63, wid = t >> 6;
    const int4* d4 = (const int4*)deg;
    int s = 0;
    #pragma unroll
    for (int j = 0; j < 8; ++j) {
        int4 v = d4[t * 8 + j];
        s += v.x + v.y + v.z + v.w;
    }
    int incl = s;
    #pragma unroll
    for (int d = 1; d < 64; d <<= 1) {
        int y = __shfl_up(incl, d, 64);
        if (lane >= d) incl += y;
    }
    if (lane == 63) wsum[wid] = incl;
    __syncthreads();
    if (t < 16) {
        int v2 = wsum[t];
        int inc2 = v2;
        #pragma unroll
        for (int d = 1; d < 16; d <<= 1) {
            int y = __shfl_up(inc2, d, 64);
            if (t >= d) inc2 += y;
        }
        wsum[t] = inc2 - v2;  // exclusive over wave totals
    }
    __syncthreads();
    int run = (incl - s) + wsum[wid];
    #pragma unroll
    for (int j = 0; j < 8; ++j) {
        int4 v = d4[t * 8 + j];
        int base = t * 32 + j * 4;
        offs[base + 0] = run; invd[base + 0] = v.x ? 1.f / (float)v.x : 0.f; run += v.x;
        offs[base + 1] = run; invd[base + 1] = v.y ? 1.f / (float)v.y : 0.f; run += v.y;
        offs[base + 2] = run; invd[base + 2] = v.z ? 1.f / (float)v.z : 0.f; run += v.z;
        offs[base + 3] = run; invd[base + 3] = v.w ? 1.f / (float)v.w : 0.f; run += v.w;
    }
    if (t == 1023) offs[NN] = run;
}

__global__ __launch_bounds__(256) void k_fill(const int* __restrict__ ei, const int* __restrict__ flags,
                                              const int* __restrict__ offs, int* __restrict__ cursor,
                                              int* __restrict__ csr) {
    int e = blockIdx.x * 256 + threadIdx.x;
    int f = flags[1];
    int d = f ? ei[2 * e] : ei[e];
    int s = f ? ei[2 * NE + 2 * e] : ei[NE + e];
    int p = atomicAdd(&cursor[d], 1);
    csr[offs[d] + p] = s;
}

// ---------------- mean aggregation (8x edge unroll => 8 gathers in flight) ----------------

__global__ __launch_bounds__(256) void k_agg0(const __bf16* __restrict__ X, const int* __restrict__ csr,
                                              const int* __restrict__ offs, const float* __restrict__ invd,
                                              __bf16* __restrict__ M) {
    const int t = threadIdx.x;
    const int n = blockIdx.x * 16 + (t >> 4);  // 16 lanes per node (128 feats)
    const size_t lo = (size_t)(t & 15) * 8;
    const int beg = offs[n], end = offs[n + 1];
    float a[8] = {};
    int e = beg;
    for (; e + 8 <= end; e += 8) {
        #pragma unroll
        for (int u = 0; u < 8; ++u) {
            bf16x8 v = *(const bf16x8*)&X[(size_t)csr[e + u] * 128 + lo];
            #pragma unroll
            for (int j = 0; j < 8; ++j) a[j] += (float)v[j];
        }
    }
    for (; e < end; ++e) {
        bf16x8 v = *(const bf16x8*)&X[(size_t)csr[e] * 128 + lo];
        #pragma unroll
        for (int j = 0; j < 8; ++j) a[j] += (float)v[j];
    }
    const float id = invd[n];
    bf16x8 o;
    #pragma unroll
    for (int j = 0; j < 8; ++j) o[j] = (__bf16)(a[j] * id);
    *(bf16x8*)&M[(size_t)n * 128 + lo] = o;
}

__global__ __launch_bounds__(256) void k_agg(const __bf16* __restrict__ X, const int* __restrict__ csr,
                                             const int* __restrict__ offs, const float* __restrict__ invd,
                                             __bf16* __restrict__ M) {
    const int t = threadIdx.x;
    const int n = blockIdx.x * 8 + (t >> 5);  // 32 lanes per node (256 feats)
    const size_t lo = (size_t)(t & 31) * 8;
    const int beg = offs[n], end = offs[n + 1];
    float a[8] = {};
    int e = beg;
    for (; e + 8 <= end; e += 8) {
        #pragma unroll
        for (int u = 0; u < 8; ++u) {
            bf16x8 v = *(const bf16x8*)&X[(size_t)csr[e + u] * HD + lo];
            #pragma unroll
            for (int j = 0; j < 8; ++j) a[j] += (float)v[j];
        }
    }
    for (; e < end; ++e) {
        bf16x8 v = *(const bf16x8*)&X[(size_t)csr[e] * HD + lo];
        #pragma unroll
        for (int j = 0; j < 8; ++j) a[j] += (float)v[j];
    }
    const float id = invd[n];
    bf16x8 o;
    #pragma unroll
    for (int j = 0; j < 8; ++j) o[j] = (__bf16)(a[j] * id);
    *(bf16x8*)&M[(size_t)n * HD + lo] = o;
}

// ---------------- MFMA GEMM: Y = A1@W1 (+ A2@W2) + bias ----------------
// 128x128 block tile, 4 waves in 2x2, wave tile 64x64 = 4x4 of 16x16x32 MFMA.
// Per wave-K-step: 16 MFMA : 8 ds_read_b128 (2:1, was 8:6).
// MODE 0 (STATS): write raw y bf16 + fp32 column sum/sumsq atomics.
// MODE 1 (DOT):   x2[row] += sum_col relu(y + bias) * W1b[col]; no O write.

template <int MODE>
__global__ __launch_bounds__(256) void k_gemm(const __bf16* __restrict__ A1, const __bf16* __restrict__ WT1,
                                              const __bf16* __restrict__ A2, const __bf16* __restrict__ WT2,
                                              const __bf16* __restrict__ bias, int KD,
                                              __bf16* __restrict__ O, float* __restrict__ colsum,
                                              const __bf16* __restrict__ W1b, float* __restrict__ x2) {
    __shared__ __bf16 As[128][40];
    __shared__ __bf16 Bs[128][40];
    const int t = threadIdx.x;
    const int lane = t & 63, w = t >> 6;
    const int wm = w >> 1, wn = w & 1;
    const int quad = lane >> 4, l15 = lane & 15;
    const int row0 = blockIdx.x * 128, c0 = blockIdx.y * 128;
    f32x4 acc[4][4] = {};
    const int sr = t >> 1, skoff = (t & 1) * 16;
    const int npass = A2 ? 2 : 1;
    for (int pass = 0; pass < npass; ++pass) {
        const __bf16* __restrict__ A = pass ? A2 : A1;
        const __bf16* __restrict__ WT = pass ? WT2 : WT1;
        for (int k0 = 0; k0 < KD; k0 += 32) {
            __syncthreads();
            const __bf16* ap = &A[(size_t)(row0 + sr) * KD + k0 + skoff];
            *(bf16x8*)&As[sr][skoff] = *(const bf16x8*)ap;
            *(bf16x8*)&As[sr][skoff + 8] = *(const bf16x8*)(ap + 8);
            const __bf16* bp = &WT[(size_t)(c0 + sr) * KD + k0 + skoff];
            *(bf16x8*)&Bs[sr][skoff] = *(const bf16x8*)bp;
            *(bf16x8*)&Bs[sr][skoff + 8] = *(const bf16x8*)(bp + 8);
            __syncthreads();
            bf16x8 af[4], bfr[4];
            #pragma unroll
            for (int i = 0; i < 4; ++i) af[i] = *(const bf16x8*)&As[wm * 64 + i * 16 + l15][quad * 8];
            #pragma unroll
            for (int j = 0; j < 4; ++j) bfr[j] = *(const bf16x8*)&Bs[wn * 64 + j * 16 + l15][quad * 8];
            #pragma unroll
            for (int i = 0; i < 4; ++i)
                #pragma unroll
                for (int j = 0; j < 4; ++j)
                    acc[i][j] = __builtin_amdgcn_mfma_f32_16x16x32_bf16(af[i], bfr[j], acc[i][j], 0, 0, 0);
        }
    }
    __syncthreads();
    if constexpr (MODE == 0) {
        float* lsum = (float*)&As[0][0];  // [0..127]=sum, [128..255]=sumsq (block cols)
        lsum[t] = 0.f;
        __syncthreads();
        #pragma unroll
        for (int j = 0; j < 4; ++j) {
            const int cb = wn * 64 + j * 16 + l15;
            const int col = c0 + cb;
            const float b = (float)bias[col];
            float s = 0.f, q = 0.f;
            #pragma unroll
            for (int i = 0; i < 4; ++i) {
                const size_t rbase = (size_t)(row0 + wm * 64 + i * 16 + quad * 4) * HD + col;
                #pragma unroll
                for (int r = 0; r < 4; ++r) {
                    float y = acc[i][j][r] + b;
                    O[rbase + (size_t)r * HD] = (__bf16)y;
                    s += y;
                    q += y * y;
                }
            }
            s += __shfl_xor(s, 16, 64); s += __shfl_xor(s, 32, 64);
            q += __shfl_xor(q, 16, 64); q += __shfl_xor(q, 32, 64);
            if (quad == 0) {
                atomicAdd(&lsum[cb], s);
                atomicAdd(&lsum[128 + cb], q);
            }
        }
        __syncthreads();
        if (t < 128) atomicAdd(&colsum[c0 + t], lsum[t]);
        else atomicAdd(&colsum[256 + c0 + t - 128], lsum[t]);
    } else {
        float bj[4], wj[4];
        #pragma unroll
        for (int j = 0; j < 4; ++j) {
            const int col = c0 + wn * 64 + j * 16 + l15;
            bj[j] = (float)bias[col];
            wj[j] = (float)W1b[col];
        }
        #pragma unroll
        for (int i = 0; i < 4; ++i) {
            #pragma unroll
            for (int r = 0; r < 4; ++r) {
                float p = 0.f;
                #pragma unroll
                for (int j = 0; j < 4; ++j) p += fmaxf(acc[i][j][r] + bj[j], 0.f) * wj[j];
                p += __shfl_xor(p, 1, 64); p += __shfl_xor(p, 2, 64);
                p += __shfl_xor(p, 4, 64); p += __shfl_xor(p, 8, 64);
                if (l15 == 0) atomicAdd(&x2[row0 + wm * 64 + i * 16 + quad * 4 + r], p);
            }
        }
    }
}

// ---------------- BN apply (params computed in-block from raw stats) ----------------

__global__ __launch_bounds__(256) void k_bnapply(__bf16* __restrict__ Y, const float* __restrict__ colsum,
                                                 const __bf16* __restrict__ gamma, const __bf16* __restrict__ beta) {
    __shared__ float sc[256], sh[256];
    const int t = threadIdx.x;
    {
        const float invn = 1.0f / NN;
        float m = colsum[t] * invn;
        float var = fmaxf(colsum[256 + t] * invn - m * m, 0.f);
        float rs = rsqrtf(var + 1e-5f);
        float s = (float)gamma[t] * rs;
        sc[t] = s;
        sh[t] = (float)beta[t] - m * s;
    }
    __syncthreads();
    size_t i = ((size_t)blockIdx.x * 256 + t) * 8;
    int c = (int)(i & 255);
    bf16x8 y = *(const bf16x8*)&Y[i];
    bf16x8 o;
    #pragma unroll
    for (int j = 0; j < 8; ++j) o[j] = (__bf16)fmaxf((float)y[j] * sc[c + j] + sh[c + j], 0.f);
    *(bf16x8*)&Y[i] = o;
}

// ---------------- fused tail: +b1b, final BN+relu, mlp2 ----------------

__global__ __launch_bounds__(256) void k_tail(const float* __restrict__ x2g, const __bf16* __restrict__ b1b,
                                              const __bf16* __restrict__ gf, const __bf16* __restrict__ bf_,
                                              const __bf16* __restrict__ W2a, const __bf16* __restrict__ b2a,
                                              const __bf16* __restrict__ W2b, const __bf16* __restrict__ b2b,
                                              const int* __restrict__ flags, void* __restrict__ out) {
    __shared__ float X3[8192];   // x2 -> x3 in place
    __shared__ __bf16 X4[8192];
    const int t = threadIdx.x;
    const float b1 = (float)b1b[0];
    for (int i = t; i < 8192; i += 256) X3[i] = x2g[i] + b1;
    __syncthreads();
    {  // final BN over batch axis (32 rows), column t
        float s = 0.f, q = 0.f;
        #pragma unroll
        for (int b = 0; b < 32; ++b) {
            float v = X3[b * 256 + t];
            s += v; q += v * v;
        }
        float m = s * (1.0f / 32.0f);
        float var = fmaxf(q * (1.0f / 32.0f) - m * m, 0.f);
        float rs = rsqrtf(var + 1e-5f);
        float scc = (float)gf[t] * rs;
        float shc = (float)bf_[t] - m * scc;
        #pragma unroll
        for (int b = 0; b < 32; ++b) X3[b * 256 + t] = fmaxf(X3[b * 256 + t] * scc + shc, 0.f);
    }
    __syncthreads();
    {  // mlp2a: X4[b][t] = relu(sum_j X3[b][j] * W2a[j][t] + b2a[t])
        float acc[32];
        const float b2 = (float)b2a[t];
        #pragma unroll
        for (int b = 0; b < 32; ++b) acc[b] = b2;
        for (int j = 0; j < 256; ++j) {
            float wv = (float)W2a[j * 256 + t];
            #pragma unroll
            for (int b = 0; b < 32; ++b) acc[b] += X3[b * 256 + j] * wv;
        }
        #pragma unroll
        for (int b = 0; b < 32; ++b) X4[b * 256 + t] = (__bf16)fmaxf(acc[b], 0.f);
    }
    __syncthreads();
    for (int o = t; o < 512; o += 256) {
        int b = o >> 4, k = o & 15;
        float acc = (float)b2b[k];
        for (int j = 0; j < 256; ++j) acc += (float)X4[b * 256 + j] * (float)W2b[j * 16 + k];
        if (flags[0]) ((__bf16*)out)[o] = (__bf16)acc;
        else ((float*)out)[o] = acc;
    }
}

// ---------------- launcher ----------------

extern "C" void kernel_launch(void* const* d_in, const int* in_sizes, int n_in,
                              void* d_out, int out_size, void* d_ws, size_t ws_size,
                              hipStream_t stream) {
    const int* ei = (const int*)d_in[4];

    char* ws = (char*)d_ws;
    size_t off_ = 0;
    auto ALLOC = [&](size_t b) { char* p = ws + off_; off_ += (b + 255) & ~(size_t)255; return p; };
    int* flags_ = (int*)ALLOC(8);
    int* deg_ = (int*)ALLOC(NN * 4);      // deg_ + cursor_ : one 256 KB memset
    int* cursor_ = (int*)ALLOC(NN * 4);
    int* offs_ = (int*)ALLOC((NN + 1) * 4);
    float* invd_ = (float*)ALLOC(NN * 4);
    float* colsum_ = (float*)ALLOC(4 * 512 * 4);  // 4 layer stat-sets; + x2: one 40 KB memset
    float* x2_ = (float*)ALLOC(8192 * 4);
    int* csr_ = (int*)ALLOC((size_t)NE * 4);
    __bf16* blob_ = (__bf16*)ALLOC((size_t)TOTP * 2);
    __bf16* M_ = (__bf16*)ALLOC((size_t)NN * HD * 2);
    __bf16* Xa_ = (__bf16*)ALLOC((size_t)NN * HD * 2);
    __bf16* Xb_ = (__bf16*)ALLOC((size_t)NN * HD * 2);  // first 8 MB doubles as X0c
    __bf16* X0c_ = Xb_;  // dead before layer-1 GEMM writes Xb

    // converted parameter views (GEMM weights transposed to [out][in])
    __bf16* Wl0T = blob_ + 0;
    __bf16* Wr0T = blob_ + 32768;
    __bf16* bb0c = blob_ + 65536;
    __bf16* WlT = blob_ + 65792;     // 3 x [256][256]
    __bf16* WrT = blob_ + 262400;
    __bf16* bbc = blob_ + 459008;
    __bf16* gammac = blob_ + 459776;
    __bf16* betac = blob_ + 460800;
    __bf16* W1aT = blob_ + 461824;   // [256][1024]
    __bf16* b1ac = blob_ + 723968;
    __bf16* W1bc = blob_ + 724224;
    __bf16* b1bc = blob_ + 724480;
    __bf16* gfc = blob_ + 724481;
    __bf16* bfc = blob_ + 724737;
    __bf16* W2ac = blob_ + 724993;   // untransposed (k-major for tail)
    __bf16* b2ac = blob_ + 790529;
    __bf16* W2bc = blob_ + 790785;
    __bf16* b2bc = blob_ + 794881;

    k_det<<<1, 128, 0, stream>>>((const unsigned*)d_in[0], ei, flags_);

    PtrTable pt;
    pt.p[0] = d_in[5];  pt.p[1] = d_in[6];  pt.p[2] = d_in[7];  pt.p[3] = d_in[8];
    pt.p[4] = d_in[9];  pt.p[5] = d_in[10]; pt.p[6] = d_in[11]; pt.p[7] = d_in[12];
    pt.p[8] = d_in[13]; pt.p[9] = d_in[14]; pt.p[10] = d_in[15]; pt.p[11] = d_in[16];
    pt.p[12] = d_in[17]; pt.p[13] = d_in[18]; pt.p[14] = d_in[19]; pt.p[15] = d_in[20];
    pt.p[16] = d_in[21]; pt.p[17] = d_in[22];
    k_cvt_params<<<(TOTP + 255) / 256, 256, 0, stream>>>(pt, flags_, blob_);
    k_cvt_x0<<<NN * 128 / 256, 256, 0, stream>>>(d_in[0], d_in[1], d_in[2], d_in[3], flags_, X0c_);

    hipMemsetAsync(deg_, 0, 2 * NN * 4, stream);                 // deg + cursor
    hipMemsetAsync(colsum_, 0, 4 * 512 * 4 + 8192 * 4, stream);  // 4 stat-sets + x2
    k_deg<<<NE / 256, 256, 0, stream>>>(ei, flags_, deg_);
    k_scan<<<1, 1024, 0, stream>>>(deg_, offs_, invd_);
    k_fill<<<NE / 256, 256, 0, stream>>>(ei, flags_, offs_, cursor_, csr_);

    // layer 0 (K=128)
    k_agg0<<<NN / 16, 256, 0, stream>>>(X0c_, csr_, offs_, invd_, M_);
    k_gemm<0><<<dim3(NN / 128, 2), 256, 0, stream>>>(M_, Wl0T, X0c_, Wr0T, bb0c, 128, Xa_, colsum_, nullptr, nullptr);
    k_bnapply<<<NN / 8, 256, 0, stream>>>(Xa_, colsum_, gammac, betac);

    // layers 1..3 (K=256), ping-pong Xa <-> Xb
    __bf16* Xin = Xa_;
    __bf16* Xo = Xb_;
    for (int l = 0; l < 3; ++l) {
        float* cs = colsum_ + (l + 1) * 512;
        k_agg<<<NN / 8, 256, 0, stream>>>(Xin, csr_, offs_, invd_, M_);
        k_gemm<0><<<dim3(NN / 128, 2), 256, 0, stream>>>(M_, WlT + (size_t)l * HD * HD, Xin,
                                                         WrT + (size_t)l * HD * HD, bbc + l * HD, 256, Xo,
                                                         cs, nullptr, nullptr);
        k_bnapply<<<NN / 8, 256, 0, stream>>>(Xo, cs, gammac + (l + 1) * HD, betac + (l + 1) * HD);
        __bf16* tmp = Xin; Xin = Xo; Xo = tmp;
    }
    // Xin = layer-3 post-BN output, flat-viewed as [8192, 1024]

    // mlp1 + W1b dot fused: x2[r] = sum_c relu((Xin@W1a)[r,c] + b1a[c]) * W1b[c]
    k_gemm<1><<<dim3(8192 / 128, 2), 256, 0, stream>>>(Xin, W1aT, nullptr, nullptr, b1ac, 1024, nullptr, nullptr,
                                                       W1bc, x2_);
    k_tail<<<1, 256, 0, stream>>>(x2_, b1bc, gfc, bfc, W2ac, b2ac, W2bc, b2bc, flags_, d_out);
}

// Round 6
// 517.340 us; speedup vs baseline: 1.4105x; 1.0751x over previous
//
#include <hip/hip_runtime.h>

#define NN 32768
#define NE 524288
#define HD 256
#define TOTP 794897

typedef __attribute__((ext_vector_type(8))) __bf16 bf16x8;
typedef __attribute__((ext_vector_type(4))) float f32x4;

// ---------------- detection (dtype of floats, layout of edge_index) ----------------
__global__ __launch_bounds__(128) void k_det(const unsigned* __restrict__ x, const int* __restrict__ ei,
                                             int* __restrict__ flags) {
    int t = threadIdx.x;
    if (t < 64) {
        unsigned L = x[t] & 0xFFFFu;
        int e = (int)((L >> 7) & 0xFF);
        unsigned long long b = __ballot(e >= 90 && e <= 135);
        if (t == 0) flags[0] = (b == ~0ULL) ? 1 : 0;  // 1 => bf16 inputs
    } else {
        int u = t - 64;
        unsigned long long b = __ballot(ei[2 * u + 1] != 0);
        if (t == 64) flags[1] = (b == 0ULL) ? 1 : 0;  // 1 => int64 edges
    }
}

// ---------------- conversion (+ weight transpose) ----------------

__device__ __forceinline__ float ld_any(const void* p, int i, int isbf16) {
    return isbf16 ? (float)((const __bf16*)p)[i] : ((const float*)p)[i];
}

struct PtrTable { const void* p[18]; };

__global__ __launch_bounds__(256) void k_cvt_params(PtrTable pt, const int* __restrict__ flags,
                                                    __bf16* __restrict__ blob) {
    const int off[23] = {0, 32768, 65536, 65792, 131328, 196864, 262400, 327936, 393472,
                         459008, 459776, 460800, 461824, 723968, 724224, 724480, 724481,
                         724737, 724993, 790529, 790785, 794881, TOTP};
    const signed char pidx[22] = {0, 1, 2, 3, 3, 3, 4, 4, 4, 5, 6, 7, 8, 9, 10, 11, 12, 13, 14, 15, 16, 17};
    const int sbase[22] = {0, 0, 0, 0, 65536, 131072, 0, 65536, 131072, 0, 0, 0, 0, 0, 0, 0, 0, 0, 0, 0, 0, 0};
    const signed char lR[22] = {7, 7, -1, 8, 8, 8, 8, 8, 8, -1, -1, -1, 10, -1, -1, -1, -1, -1, -1, -1, -1, -1};
    const signed char lC[22] = {8, 8, 0, 8, 8, 8, 8, 8, 8, 0, 0, 0, 8, 0, 0, 0, 0, 0, 0, 0, 0, 0};
    int i = blockIdx.x * 256 + threadIdx.x;
    if (i >= TOTP) return;
    int s = 0;
    while (i >= off[s + 1]) ++s;
    int j = i - off[s];
    int si;
    if (lR[s] >= 0) {
        int Rm = (1 << lR[s]) - 1;
        si = sbase[s] + ((j & Rm) << lC[s]) + (j >> lR[s]);  // transpose read
    } else {
        si = sbase[s] + j;
    }
    blob[i] = (__bf16)ld_any(pt.p[pidx[s]], si, flags[0]);
}

__global__ __launch_bounds__(256) void k_cvt_x0(const void* __restrict__ p0, const void* __restrict__ p1,
                                                const void* __restrict__ p2, const void* __restrict__ p3,
                                                const int* __restrict__ flags, __bf16* __restrict__ X0c) {
    int i = blockIdx.x * 256 + threadIdx.x;  // NN*128
    int n = i >> 7, f = i & 127;
    const void* src = (f < 32) ? p0 : (f < 64) ? p1 : (f < 96) ? p2 : p3;
    X0c[i] = (__bf16)ld_any(src, n * 32 + (f & 31), flags[0]);
}

// ---------------- CSR build ----------------

__global__ __launch_bounds__(256) void k_deg(const int* __restrict__ ei, const int* __restrict__ flags,
                                             int* __restrict__ deg) {
    int e = blockIdx.x * 256 + threadIdx.x;
    int d = flags[1] ? ei[2 * e] : ei[e];
    atomicAdd(&deg[d], 1);
}

__global__ __launch_bounds__(1024) void k_scan(const int* __restrict__ deg, int* __restrict__ offs,
                                               float* __restrict__ invd) {
    __shared__ int wsum[16];
    const int t = threadIdx.x, lane = t & 63, wid = t >> 6;
    const int4* d4 = (const int4*)deg;
    int s = 0;
    #pragma unroll
    for (int j = 0; j < 8; ++j) {
        int4 v = d4[t * 8 + j];
        s += v.x + v.y + v.z + v.w;
    }
    int incl = s;
    #pragma unroll
    for (int d = 1; d < 64; d <<= 1) {
        int y = __shfl_up(incl, d, 64);
        if (lane >= d) incl += y;
    }
    if (lane == 63) wsum[wid] = incl;
    __syncthreads();
    if (t < 16) {
        int v2 = wsum[t];
        int inc2 = v2;
        #pragma unroll
        for (int d = 1; d < 16; d <<= 1) {
            int y = __shfl_up(inc2, d, 64);
            if (t >= d) inc2 += y;
        }
        wsum[t] = inc2 - v2;  // exclusive over wave totals
    }
    __syncthreads();
    int run = (incl - s) + wsum[wid];
    #pragma unroll
    for (int j = 0; j < 8; ++j) {
        int4 v = d4[t * 8 + j];
        int base = t * 32 + j * 4;
        offs[base + 0] = run; invd[base + 0] = v.x ? 1.f / (float)v.x : 0.f; run += v.x;
        offs[base + 1] = run; invd[base + 1] = v.y ? 1.f / (float)v.y : 0.f; run += v.y;
        offs[base + 2] = run; invd[base + 2] = v.z ? 1.f / (float)v.z : 0.f; run += v.z;
        offs[base + 3] = run; invd[base + 3] = v.w ? 1.f / (float)v.w : 0.f; run += v.w;
    }
    if (t == 1023) offs[NN] = run;
}

__global__ __launch_bounds__(256) void k_fill(const int* __restrict__ ei, const int* __restrict__ flags,
                                              const int* __restrict__ offs, int* __restrict__ cursor,
                                              int* __restrict__ csr) {
    int e = blockIdx.x * 256 + threadIdx.x;
    int f = flags[1];
    int d = f ? ei[2 * e] : ei[e];
    int s = f ? ei[2 * NE + 2 * e] : ei[NE + e];
    int p = atomicAdd(&cursor[d], 1);
    csr[offs[d] + p] = s;
}

// ---------------- mean aggregation ----------------
// 8x edge unroll => 8 independent 512B gathers in flight per wave.
// BN: gathered rows are RAW pre-BN gemm output; apply sc*y+sh, relu in fp32
// before accumulating (sc/sh computed per lane from column stats).

__global__ __launch_bounds__(256) void k_agg0(const __bf16* __restrict__ X, const int* __restrict__ csr,
                                              const int* __restrict__ offs, const float* __restrict__ invd,
                                              __bf16* __restrict__ M) {
    const int t = threadIdx.x;
    const int n = blockIdx.x * 16 + (t >> 4);  // 16 lanes per node (128 feats)
    const size_t lo = (size_t)(t & 15) * 8;
    const int beg = offs[n], end = offs[n + 1];
    float a[8] = {};
    int e = beg;
    for (; e + 8 <= end; e += 8) {
        #pragma unroll
        for (int u = 0; u < 8; ++u) {
            bf16x8 v = *(const bf16x8*)&X[(size_t)csr[e + u] * 128 + lo];
            #pragma unroll
            for (int j = 0; j < 8; ++j) a[j] += (float)v[j];
        }
    }
    for (; e < end; ++e) {
        bf16x8 v = *(const bf16x8*)&X[(size_t)csr[e] * 128 + lo];
        #pragma unroll
        for (int j = 0; j < 8; ++j) a[j] += (float)v[j];
    }
    const float id = invd[n];
    bf16x8 o;
    #pragma unroll
    for (int j = 0; j < 8; ++j) o[j] = (__bf16)(a[j] * id);
    *(bf16x8*)&M[(size_t)n * 128 + lo] = o;
}

__global__ __launch_bounds__(256) void k_agg(const __bf16* __restrict__ X, const int* __restrict__ csr,
                                             const int* __restrict__ offs, const float* __restrict__ invd,
                                             const float* __restrict__ pstat, const __bf16* __restrict__ pg,
                                             const __bf16* __restrict__ pb, __bf16* __restrict__ M) {
    const int t = threadIdx.x;
    const int n = blockIdx.x * 8 + (t >> 5);  // 32 lanes per node (256 feats)
    const int c0 = (t & 31) * 8;
    const size_t lo = (size_t)c0;
    float sc[8], sh[8];
    {
        const float invn = 1.0f / NN;
        #pragma unroll
        for (int j = 0; j < 8; ++j) {
            int c = c0 + j;
            float m = pstat[c] * invn;
            float var = fmaxf(pstat[256 + c] * invn - m * m, 0.f);
            float rs = rsqrtf(var + 1e-5f);
            sc[j] = (float)pg[c] * rs;
            sh[j] = (float)pb[c] - m * sc[j];
        }
    }
    const int beg = offs[n], end = offs[n + 1];
    float a[8] = {};
    int e = beg;
    for (; e + 8 <= end; e += 8) {
        #pragma unroll
        for (int u = 0; u < 8; ++u) {
            bf16x8 v = *(const bf16x8*)&X[(size_t)csr[e + u] * HD + lo];
            #pragma unroll
            for (int j = 0; j < 8; ++j) a[j] += fmaxf((float)v[j] * sc[j] + sh[j], 0.f);
        }
    }
    for (; e < end; ++e) {
        bf16x8 v = *(const bf16x8*)&X[(size_t)csr[e] * HD + lo];
        #pragma unroll
        for (int j = 0; j < 8; ++j) a[j] += fmaxf((float)v[j] * sc[j] + sh[j], 0.f);
    }
    const float id = invd[n];
    bf16x8 o;
    #pragma unroll
    for (int j = 0; j < 8; ++j) o[j] = (__bf16)(a[j] * id);
    *(bf16x8*)&M[(size_t)n * HD + lo] = o;
}

// ---------------- MFMA GEMM: Y = A1@W1 (+ A2@W2) + bias ----------------
// 128x128 block tile, 4 waves in 2x2, wave tile 64x64 = 4x4 of 16x16x32 MFMA.
// MODE 0: write raw y bf16 + fp32 column sum/sumsq atomics.
// MODE 1: x2[row] += sum_col relu(y + bias) * W1b[col]; no O write.
// BNA 0: none; 1: BN+relu applied to A2 during staging; 2: to A1.
// BN feature index = staged column & 255 (A1 of mode 1 is [8192,1024] view).

template <int MODE, int BNA>
__global__ __launch_bounds__(256) void k_gemm(const __bf16* __restrict__ A1, const __bf16* __restrict__ WT1,
                                              const __bf16* __restrict__ A2, const __bf16* __restrict__ WT2,
                                              const __bf16* __restrict__ bias, int KD,
                                              __bf16* __restrict__ O, float* __restrict__ colsum,
                                              const __bf16* __restrict__ W1b, float* __restrict__ x2,
                                              const float* __restrict__ pstat, const __bf16* __restrict__ pg,
                                              const __bf16* __restrict__ pb) {
    __shared__ __bf16 As[128][40];
    __shared__ __bf16 Bs[128][40];
    __shared__ float scs[256], shs[256];
    const int t = threadIdx.x;
    const int lane = t & 63, w = t >> 6;
    const int wm = w >> 1, wn = w & 1;
    const int quad = lane >> 4, l15 = lane & 15;
    const int row0 = blockIdx.x * 128, c0 = blockIdx.y * 128;
    if (BNA) {
        const float invn = 1.0f / NN;
        float m = pstat[t] * invn;
        float var = fmaxf(pstat[256 + t] * invn - m * m, 0.f);
        float rs = rsqrtf(var + 1e-5f);
        float s = (float)pg[t] * rs;
        scs[t] = s;
        shs[t] = (float)pb[t] - m * s;
        // visibility: covered by the __syncthreads() at the top of the K loop
    }
    f32x4 acc[4][4] = {};
    const int sr = t >> 1, skoff = (t & 1) * 16;
    const int npass = A2 ? 2 : 1;
    for (int pass = 0; pass < npass; ++pass) {
        const __bf16* __restrict__ A = pass ? A2 : A1;
        const __bf16* __restrict__ WT = pass ? WT2 : WT1;
        const bool applybn = (BNA == 1 && pass == 1) || (BNA == 2 && pass == 0);
        for (int k0 = 0; k0 < KD; k0 += 32) {
            __syncthreads();
            const __bf16* ap = &A[(size_t)(row0 + sr) * KD + k0 + skoff];
            bf16x8 r0 = *(const bf16x8*)ap;
            bf16x8 r1 = *(const bf16x8*)(ap + 8);
            if (applybn) {
                const int cb = (k0 + skoff) & 255;
                #pragma unroll
                for (int j = 0; j < 8; ++j) {
                    r0[j] = (__bf16)fmaxf((float)r0[j] * scs[cb + j] + shs[cb + j], 0.f);
                    r1[j] = (__bf16)fmaxf((float)r1[j] * scs[cb + 8 + j] + shs[cb + 8 + j], 0.f);
                }
            }
            *(bf16x8*)&As[sr][skoff] = r0;
            *(bf16x8*)&As[sr][skoff + 8] = r1;
            const __bf16* bp = &WT[(size_t)(c0 + sr) * KD + k0 + skoff];
            *(bf16x8*)&Bs[sr][skoff] = *(const bf16x8*)bp;
            *(bf16x8*)&Bs[sr][skoff + 8] = *(const bf16x8*)(bp + 8);
            __syncthreads();
            bf16x8 af[4], bfr[4];
            #pragma unroll
            for (int i = 0; i < 4; ++i) af[i] = *(const bf16x8*)&As[wm * 64 + i * 16 + l15][quad * 8];
            #pragma unroll
            for (int j = 0; j < 4; ++j) bfr[j] = *(const bf16x8*)&Bs[wn * 64 + j * 16 + l15][quad * 8];
            #pragma unroll
            for (int i = 0; i < 4; ++i)
                #pragma unroll
                for (int j = 0; j < 4; ++j)
                    acc[i][j] = __builtin_amdgcn_mfma_f32_16x16x32_bf16(af[i], bfr[j], acc[i][j], 0, 0, 0);
        }
    }
    __syncthreads();
    if constexpr (MODE == 0) {
        float* lsum = (float*)&As[0][0];  // [0..127]=sum, [128..255]=sumsq (block cols)
        lsum[t] = 0.f;
        __syncthreads();
        #pragma unroll
        for (int j = 0; j < 4; ++j) {
            const int cb = wn * 64 + j * 16 + l15;
            const int col = c0 + cb;
            const float b = (float)bias[col];
            float s = 0.f, q = 0.f;
            #pragma unroll
            for (int i = 0; i < 4; ++i) {
                const size_t rbase = (size_t)(row0 + wm * 64 + i * 16 + quad * 4) * HD + col;
                #pragma unroll
                for (int r = 0; r < 4; ++r) {
                    float y = acc[i][j][r] + b;
                    O[rbase + (size_t)r * HD] = (__bf16)y;
                    s += y;
                    q += y * y;
                }
            }
            s += __shfl_xor(s, 16, 64); s += __shfl_xor(s, 32, 64);
            q += __shfl_xor(q, 16, 64); q += __shfl_xor(q, 32, 64);
            if (quad == 0) {
                atomicAdd(&lsum[cb], s);
                atomicAdd(&lsum[128 + cb], q);
            }
        }
        __syncthreads();
        if (t < 128) atomicAdd(&colsum[c0 + t], lsum[t]);
        else atomicAdd(&colsum[256 + c0 + t - 128], lsum[t]);
    } else {
        float bj[4], wj[4];
        #pragma unroll
        for (int j = 0; j < 4; ++j) {
            const int col = c0 + wn * 64 + j * 16 + l15;
            bj[j] = (float)bias[col];
            wj[j] = (float)W1b[col];
        }
        #pragma unroll
        for (int i = 0; i < 4; ++i) {
            #pragma unroll
            for (int r = 0; r < 4; ++r) {
                float p = 0.f;
                #pragma unroll
                for (int j = 0; j < 4; ++j) p += fmaxf(acc[i][j][r] + bj[j], 0.f) * wj[j];
                p += __shfl_xor(p, 1, 64); p += __shfl_xor(p, 2, 64);
                p += __shfl_xor(p, 4, 64); p += __shfl_xor(p, 8, 64);
                if (l15 == 0) atomicAdd(&x2[row0 + wm * 64 + i * 16 + quad * 4 + r], p);
            }
        }
    }
}

// ---------------- tail (parallel): bnf (1 block) + mlp2 (32 blocks) ----------------

__global__ __launch_bounds__(256) void k_bnf(const float* __restrict__ x2, const __bf16* __restrict__ b1b,
                                             const __bf16* __restrict__ gf, const __bf16* __restrict__ bf_,
                                             float* __restrict__ x3) {
    int c = threadIdx.x;
    const float b1 = (float)b1b[0];
    float v[32];
    float s = 0.f, q = 0.f;
    #pragma unroll
    for (int b = 0; b < 32; ++b) {
        v[b] = x2[b * HD + c] + b1;
        s += v[b];
        q += v[b] * v[b];
    }
    float m = s * (1.0f / 32.0f);
    float var = fmaxf(q * (1.0f / 32.0f) - m * m, 0.f);
    float rs = rsqrtf(var + 1e-5f);
    float sc = (float)gf[c] * rs;
    float sh = (float)bf_[c] - m * sc;
    #pragma unroll
    for (int b = 0; b < 32; ++b) x3[b * HD + c] = fmaxf(v[b] * sc + sh, 0.f);
}

__global__ __launch_bounds__(256) void k_mlp2(const float* __restrict__ x3, const __bf16* __restrict__ W2a,
                                              const __bf16* __restrict__ b2a, const __bf16* __restrict__ W2b,
                                              const __bf16* __restrict__ b2b, const int* __restrict__ flags,
                                              void* __restrict__ out) {
    __shared__ float row[HD];
    __shared__ float hbuf[HD];
    __shared__ float part[256];
    const int b = blockIdx.x, t = threadIdx.x;
    row[t] = x3[b * HD + t];
    __syncthreads();
    float acc = (float)b2a[t];
    for (int j = 0; j < HD; ++j) acc += row[j] * (float)W2a[j * HD + t];
    hbuf[t] = fmaxf(acc, 0.f);
    __syncthreads();
    const int k = t & 15, g = t >> 4;
    float p = 0.f;
    #pragma unroll
    for (int jj = 0; jj < 16; ++jj) p += hbuf[g * 16 + jj] * (float)W2b[(g * 16 + jj) * 16 + k];
    part[t] = p;
    __syncthreads();
    if (t < 16) {
        float s = (float)b2b[t];
        #pragma unroll
        for (int g2 = 0; g2 < 16; ++g2) s += part[g2 * 16 + t];
        if (flags[0]) ((__bf16*)out)[b * 16 + t] = (__bf16)s;
        else ((float*)out)[b * 16 + t] = s;
    }
}

// ---------------- launcher ----------------

extern "C" void kernel_launch(void* const* d_in, const int* in_sizes, int n_in,
                              void* d_out, int out_size, void* d_ws, size_t ws_size,
                              hipStream_t stream) {
    const int* ei = (const int*)d_in[4];

    char* ws = (char*)d_ws;
    size_t off_ = 0;
    auto ALLOC = [&](size_t b) { char* p = ws + off_; off_ += (b + 255) & ~(size_t)255; return p; };
    int* flags_ = (int*)ALLOC(8);
    int* deg_ = (int*)ALLOC(NN * 4);      // deg_ + cursor_ : one 256 KB memset
    int* cursor_ = (int*)ALLOC(NN * 4);
    int* offs_ = (int*)ALLOC((NN + 1) * 4);
    float* invd_ = (float*)ALLOC(NN * 4);
    float* colsum_ = (float*)ALLOC(4 * 512 * 4);  // stats slot l = conv layer l; + x2: one memset
    float* x2_ = (float*)ALLOC(8192 * 4);
    float* x3_ = (float*)ALLOC(8192 * 4);
    int* csr_ = (int*)ALLOC((size_t)NE * 4);
    __bf16* blob_ = (__bf16*)ALLOC((size_t)TOTP * 2);
    __bf16* M_ = (__bf16*)ALLOC((size_t)NN * HD * 2);
    __bf16* Xa_ = (__bf16*)ALLOC((size_t)NN * HD * 2);
    __bf16* Xb_ = (__bf16*)ALLOC((size_t)NN * HD * 2);  // first 8 MB doubles as X0c
    __bf16* X0c_ = Xb_;  // dead before layer-1 GEMM writes Xb

    // converted parameter views (GEMM weights transposed to [out][in])
    __bf16* Wl0T = blob_ + 0;
    __bf16* Wr0T = blob_ + 32768;
    __bf16* bb0c = blob_ + 65536;
    __bf16* WlT = blob_ + 65792;     // 3 x [256][256]
    __bf16* WrT = blob_ + 262400;
    __bf16* bbc = blob_ + 459008;
    __bf16* gammac = blob_ + 459776;
    __bf16* betac = blob_ + 460800;
    __bf16* W1aT = blob_ + 461824;   // [256][1024]
    __bf16* b1ac = blob_ + 723968;
    __bf16* W1bc = blob_ + 724224;
    __bf16* b1bc = blob_ + 724480;
    __bf16* gfc = blob_ + 724481;
    __bf16* bfc = blob_ + 724737;
    __bf16* W2ac = blob_ + 724993;   // untransposed (k-major for tail)
    __bf16* b2ac = blob_ + 790529;
    __bf16* W2bc = blob_ + 790785;
    __bf16* b2bc = blob_ + 794881;

    k_det<<<1, 128, 0, stream>>>((const unsigned*)d_in[0], ei, flags_);

    PtrTable pt;
    pt.p[0] = d_in[5];  pt.p[1] = d_in[6];  pt.p[2] = d_in[7];  pt.p[3] = d_in[8];
    pt.p[4] = d_in[9];  pt.p[5] = d_in[10]; pt.p[6] = d_in[11]; pt.p[7] = d_in[12];
    pt.p[8] = d_in[13]; pt.p[9] = d_in[14]; pt.p[10] = d_in[15]; pt.p[11] = d_in[16];
    pt.p[12] = d_in[17]; pt.p[13] = d_in[18]; pt.p[14] = d_in[19]; pt.p[15] = d_in[20];
    pt.p[16] = d_in[21]; pt.p[17] = d_in[22];
    k_cvt_params<<<(TOTP + 255) / 256, 256, 0, stream>>>(pt, flags_, blob_);
    k_cvt_x0<<<NN * 128 / 256, 256, 0, stream>>>(d_in[0], d_in[1], d_in[2], d_in[3], flags_, X0c_);

    hipMemsetAsync(deg_, 0, 2 * NN * 4, stream);                 // deg + cursor
    hipMemsetAsync(colsum_, 0, 4 * 512 * 4 + 8192 * 4, stream);  // 4 stat slots + x2
    k_deg<<<NE / 256, 256, 0, stream>>>(ei, flags_, deg_);
    k_scan<<<1, 1024, 0, stream>>>(deg_, offs_, invd_);
    k_fill<<<NE / 256, 256, 0, stream>>>(ei, flags_, offs_, cursor_, csr_);

    // layer 0 (K=128): inputs raw, no BN on A operands
    k_agg0<<<NN / 16, 256, 0, stream>>>(X0c_, csr_, offs_, invd_, M_);
    k_gemm<0, 0><<<dim3(NN / 128, 2), 256, 0, stream>>>(M_, Wl0T, X0c_, Wr0T, bb0c, 128, Xa_, colsum_,
                                                        nullptr, nullptr, nullptr, nullptr, nullptr);

    // layers 1..3 (K=256): consume RAW Y of prev layer + its BN params (fused)
    __bf16* Yin = Xa_;
    __bf16* Yo = Xb_;
    for (int l = 0; l < 3; ++l) {
        const float* ps = colsum_ + l * 512;          // stats of conv layer l
        const __bf16* pg = gammac + l * HD;
        const __bf16* pb = betac + l * HD;
        float* cs = colsum_ + (l + 1) * 512;          // stats produced for layer l+1
        k_agg<<<NN / 8, 256, 0, stream>>>(Yin, csr_, offs_, invd_, ps, pg, pb, M_);
        k_gemm<0, 1><<<dim3(NN / 128, 2), 256, 0, stream>>>(M_, WlT + (size_t)l * HD * HD, Yin,
                                                            WrT + (size_t)l * HD * HD, bbc + l * HD, 256, Yo,
                                                            cs, nullptr, nullptr, ps, pg, pb);
        __bf16* tmp = Yin; Yin = Yo; Yo = tmp;
    }
    // Yin = RAW layer-3 output; BN3 applied during mlp1 A-staging (flat view [8192,1024])

    k_gemm<1, 2><<<dim3(8192 / 128, 2), 256, 0, stream>>>(Yin, W1aT, nullptr, nullptr, b1ac, 1024, nullptr, nullptr,
                                                          W1bc, x2_, colsum_ + 3 * 512, gammac + 3 * HD,
                                                          betac + 3 * HD);
    k_bnf<<<1, 256, 0, stream>>>(x2_, b1bc, gfc, bfc, x3_);
    k_mlp2<<<32, 256, 0, stream>>>(x3_, W2ac, b2ac, W2bc, b2bc, flags_, d_out);
}

// Round 7
// 500.359 us; speedup vs baseline: 1.4583x; 1.0339x over previous
//
#include <hip/hip_runtime.h>

#define NN 32768
#define NE 524288
#define HD 256
#define TOTP 794897

#define GAS __attribute__((address_space(1)))
#define LAS __attribute__((address_space(3)))

typedef __attribute__((ext_vector_type(8))) __bf16 bf16x8;
typedef __attribute__((ext_vector_type(4))) float f32x4;

__device__ __forceinline__ float ld_any(const void* p, int i, int isbf16) {
    return isbf16 ? (float)((const __bf16*)p)[i] : ((const float*)p)[i];
}

struct PtrTable { const void* p[18]; };

// ---------------- fused preprocessing: detect + cvt_params + cvt_x0 + deg ----------------
// grid: [0,2048) x0-concat-convert, [2048,3601) param convert+transpose, [3601,4625) degree.
// Each block re-derives flags locally (L2-hot 1KB reads) to avoid a separate detect pass.

__global__ __launch_bounds__(256) void k_pre(const unsigned* __restrict__ xw, const int* __restrict__ ei,
                                             PtrTable pt, const void* __restrict__ p0, const void* __restrict__ p1,
                                             const void* __restrict__ p2, const void* __restrict__ p3,
                                             int* __restrict__ flags, int* __restrict__ deg,
                                             __bf16* __restrict__ blob, __bf16* __restrict__ X0c) {
    __shared__ int fl[2];
    const int t = threadIdx.x;
    if (t < 64) {
        unsigned L = xw[t] & 0xFFFFu;
        int e = (int)((L >> 7) & 0xFF);
        unsigned long long b = __ballot(e >= 90 && e <= 135);
        if (t == 0) fl[0] = (b == ~0ULL) ? 1 : 0;  // 1 => bf16 inputs
    } else if (t < 128) {
        int u = t - 64;
        unsigned long long b = __ballot(ei[2 * u + 1] != 0);
        if (t == 64) fl[1] = (b == 0ULL) ? 1 : 0;  // 1 => int64 edges
    }
    __syncthreads();
    const int f0 = fl[0], f1 = fl[1];
    const int blk = blockIdx.x;
    if (blk == 0 && t < 2) flags[t] = fl[t];
    if (blk < 2048) {
        // X0 concat: 8 consecutive elems/thread (stays within one 32-wide source)
        int i0 = (blk * 256 + t) * 8;
        int n = i0 >> 7, f = i0 & 127;
        const void* src = (f < 32) ? p0 : (f < 64) ? p1 : (f < 96) ? p2 : p3;
        int si = n * 32 + (f & 31);
        bf16x8 o;
        #pragma unroll
        for (int j = 0; j < 8; ++j) o[j] = (__bf16)ld_any(src, si + j, f0);
        *(bf16x8*)&X0c[i0] = o;
    } else if (blk < 3601) {
        const int off[23] = {0, 32768, 65536, 65792, 131328, 196864, 262400, 327936, 393472,
                             459008, 459776, 460800, 461824, 723968, 724224, 724480, 724481,
                             724737, 724993, 790529, 790785, 794881, TOTP};
        const signed char pidx[22] = {0, 1, 2, 3, 3, 3, 4, 4, 4, 5, 6, 7, 8, 9, 10, 11, 12, 13, 14, 15, 16, 17};
        const int sbase[22] = {0, 0, 0, 0, 65536, 131072, 0, 65536, 131072, 0, 0, 0, 0, 0, 0, 0, 0, 0, 0, 0, 0, 0};
        const signed char lR[22] = {7, 7, -1, 8, 8, 8, 8, 8, 8, -1, -1, -1, 10, -1, -1, -1, -1, -1, -1, -1, -1, -1};
        const signed char lC[22] = {8, 8, 0, 8, 8, 8, 8, 8, 8, 0, 0, 0, 8, 0, 0, 0, 0, 0, 0, 0, 0, 0};
        int base = ((blk - 2048) * 256 + t) * 2;
        #pragma unroll
        for (int j = 0; j < 2; ++j) {
            int i = base + j;
            if (i >= TOTP) break;
            int s = 0;
            while (i >= off[s + 1]) ++s;
            int jj = i - off[s];
            int si;
            if (lR[s] >= 0) {
                int Rm = (1 << lR[s]) - 1;
                si = sbase[s] + ((jj & Rm) << lC[s]) + (jj >> lR[s]);  // transpose read
            } else {
                si = sbase[s] + jj;
            }
            blob[i] = (__bf16)ld_any(pt.p[pidx[s]], si, f0);
        }
    } else {
        int e0 = ((blk - 3601) * 256 + t) * 2;
        int d0 = f1 ? ei[2 * e0] : ei[e0];
        int d1 = f1 ? ei[2 * e0 + 2] : ei[e0 + 1];
        atomicAdd(&deg[d0], 1);
        atomicAdd(&deg[d1], 1);
    }
}

// ---------------- CSR scan + fill ----------------

__global__ __launch_bounds__(1024) void k_scan(const int* __restrict__ deg, int* __restrict__ offs,
                                               float* __restrict__ invd) {
    __shared__ int wsum[16];
    const int t = threadIdx.x, lane = t & 63, wid = t >> 6;
    const int4* d4 = (const int4*)deg;
    int s = 0;
    #pragma unroll
    for (int j = 0; j < 8; ++j) {
        int4 v = d4[t * 8 + j];
        s += v.x + v.y + v.z + v.w;
    }
    int incl = s;
    #pragma unroll
    for (int d = 1; d < 64; d <<= 1) {
        int y = __shfl_up(incl, d, 64);
        if (lane >= d) incl += y;
    }
    if (lane == 63) wsum[wid] = incl;
    __syncthreads();
    if (t < 16) {
        int v2 = wsum[t];
        int inc2 = v2;
        #pragma unroll
        for (int d = 1; d < 16; d <<= 1) {
            int y = __shfl_up(inc2, d, 64);
            if (t >= d) inc2 += y;
        }
        wsum[t] = inc2 - v2;  // exclusive over wave totals
    }
    __syncthreads();
    int run = (incl - s) + wsum[wid];
    #pragma unroll
    for (int j = 0; j < 8; ++j) {
        int4 v = d4[t * 8 + j];
        int base = t * 32 + j * 4;
        offs[base + 0] = run; invd[base + 0] = v.x ? 1.f / (float)v.x : 0.f; run += v.x;
        offs[base + 1] = run; invd[base + 1] = v.y ? 1.f / (float)v.y : 0.f; run += v.y;
        offs[base + 2] = run; invd[base + 2] = v.z ? 1.f / (float)v.z : 0.f; run += v.z;
        offs[base + 3] = run; invd[base + 3] = v.w ? 1.f / (float)v.w : 0.f; run += v.w;
    }
    if (t == 1023) offs[NN] = run;
}

__global__ __launch_bounds__(256) void k_fill(const int* __restrict__ ei, const int* __restrict__ flags,
                                              const int* __restrict__ offs, int* __restrict__ cursor,
                                              int* __restrict__ csr) {
    int e = blockIdx.x * 256 + threadIdx.x;
    int f = flags[1];
    int d = f ? ei[2 * e] : ei[e];
    int s = f ? ei[2 * NE + 2 * e] : ei[NE + e];
    int p = atomicAdd(&cursor[d], 1);
    csr[offs[d] + p] = s;
}

// ---------------- mean aggregation (8 independent gathers in flight) ----------------

__global__ __launch_bounds__(256) void k_agg0(const __bf16* __restrict__ X, const int* __restrict__ csr,
                                              const int* __restrict__ offs, const float* __restrict__ invd,
                                              __bf16* __restrict__ M) {
    const int t = threadIdx.x;
    const int n = blockIdx.x * 16 + (t >> 4);
    const size_t lo = (size_t)(t & 15) * 8;
    const int beg = offs[n], end = offs[n + 1];
    float a[8] = {};
    int e = beg;
    for (; e + 8 <= end; e += 8) {
        #pragma unroll
        for (int u = 0; u < 8; ++u) {
            bf16x8 v = *(const bf16x8*)&X[(size_t)csr[e + u] * 128 + lo];
            #pragma unroll
            for (int j = 0; j < 8; ++j) a[j] += (float)v[j];
        }
    }
    for (; e < end; ++e) {
        bf16x8 v = *(const bf16x8*)&X[(size_t)csr[e] * 128 + lo];
        #pragma unroll
        for (int j = 0; j < 8; ++j) a[j] += (float)v[j];
    }
    const float id = invd[n];
    bf16x8 o;
    #pragma unroll
    for (int j = 0; j < 8; ++j) o[j] = (__bf16)(a[j] * id);
    *(bf16x8*)&M[(size_t)n * 128 + lo] = o;
}

__global__ __launch_bounds__(256) void k_agg(const __bf16* __restrict__ X, const int* __restrict__ csr,
                                             const int* __restrict__ offs, const float* __restrict__ invd,
                                             const float* __restrict__ pstat, const __bf16* __restrict__ pg,
                                             const __bf16* __restrict__ pb, __bf16* __restrict__ M) {
    const int t = threadIdx.x;
    const int n = blockIdx.x * 8 + (t >> 5);
    const int c0 = (t & 31) * 8;
    const size_t lo = (size_t)c0;
    float sc[8], sh[8];
    {
        const float invn = 1.0f / NN;
        #pragma unroll
        for (int j = 0; j < 8; ++j) {
            int c = c0 + j;
            float m = pstat[c] * invn;
            float var = fmaxf(pstat[256 + c] * invn - m * m, 0.f);
            float rs = rsqrtf(var + 1e-5f);
            sc[j] = (float)pg[c] * rs;
            sh[j] = (float)pb[c] - m * sc[j];
        }
    }
    const int beg = offs[n], end = offs[n + 1];
    float a[8] = {};
    int e = beg;
    for (; e + 8 <= end; e += 8) {
        #pragma unroll
        for (int u = 0; u < 8; ++u) {
            bf16x8 v = *(const bf16x8*)&X[(size_t)csr[e + u] * HD + lo];
            #pragma unroll
            for (int j = 0; j < 8; ++j) a[j] += fmaxf((float)v[j] * sc[j] + sh[j], 0.f);
        }
    }
    for (; e < end; ++e) {
        bf16x8 v = *(const bf16x8*)&X[(size_t)csr[e] * HD + lo];
        #pragma unroll
        for (int j = 0; j < 8; ++j) a[j] += fmaxf((float)v[j] * sc[j] + sh[j], 0.f);
    }
    const float id = invd[n];
    bf16x8 o;
    #pragma unroll
    for (int j = 0; j < 8; ++j) o[j] = (__bf16)(a[j] * id);
    *(bf16x8*)&M[(size_t)n * HD + lo] = o;
}

// ---------------- MFMA GEMM (m97-style staging): Y = A1@W1 (+ A2@W2) + bias ----------------
// TM x 128 block tile, 4 waves 2x2, wave tile (TM/2)x64, 16x16x32 MFMA.
// Unpadded LDS [*][32]; global_load_lds 16B DMA staging for B always and A when
// no BN transform; BN-A passes stage via VGPR + ds_write into the same layout.
// MODE 0: write raw y bf16 + fp32 column sum/sumsq atomics.
// MODE 1: x2[row] += sum_col relu(y + bias) * W1b[col]; no O write.
// BNA 0: none; 1: BN+relu on A2 staging; 2: on A1 staging (feat = col & 255).

template <int MODE, int BNA, int TM>
__global__ __launch_bounds__(256) void k_gemm(const __bf16* __restrict__ A1, const __bf16* __restrict__ WT1,
                                              const __bf16* __restrict__ A2, const __bf16* __restrict__ WT2,
                                              const __bf16* __restrict__ bias, int KD,
                                              __bf16* __restrict__ O, float* __restrict__ colsum,
                                              const __bf16* __restrict__ W1b, float* __restrict__ x2,
                                              const float* __restrict__ pstat, const __bf16* __restrict__ pg,
                                              const __bf16* __restrict__ pb) {
    constexpr int MI = TM / 32;  // m-frags per wave
    __shared__ __bf16 As[TM][32];
    __shared__ __bf16 Bs[128][32];
    __shared__ float scs[256], shs[256];
    const int t = threadIdx.x;
    const int lane = t & 63, w = t >> 6;
    const int wm = w >> 1, wn = w & 1;
    const int quad = lane >> 4, l15 = lane & 15;
    const int row0 = blockIdx.x * TM, c0 = blockIdx.y * 128;
    const int dr = lane >> 2, dc = (lane & 3) * 8;  // DMA lane mapping (16 rows x 32 cols / instr)
    if (BNA) {
        const float invn = 1.0f / NN;
        float m = pstat[t] * invn;
        float var = fmaxf(pstat[256 + t] * invn - m * m, 0.f);
        float rs = rsqrtf(var + 1e-5f);
        float s = (float)pg[t] * rs;
        scs[t] = s;
        shs[t] = (float)pb[t] - m * s;
    }
    f32x4 acc[MI][4] = {};
    const int npass = A2 ? 2 : 1;
    for (int pass = 0; pass < npass; ++pass) {
        const __bf16* __restrict__ A = pass ? A2 : A1;
        const __bf16* __restrict__ WT = pass ? WT2 : WT1;
        const bool applybn = (BNA == 1 && pass == 1) || (BNA == 2 && pass == 0);
        for (int k0 = 0; k0 < KD; k0 += 32) {
            __syncthreads();
            #pragma unroll
            for (int i = 0; i < 2; ++i) {
                const __bf16* g = &WT[(size_t)(c0 + w * 32 + i * 16 + dr) * KD + k0 + dc];
                __builtin_amdgcn_global_load_lds((const GAS void*)g, (LAS void*)&Bs[w * 32 + i * 16][0], 16, 0, 0);
            }
            if (!applybn) {
                #pragma unroll
                for (int i = 0; i < TM / 64; ++i) {
                    const __bf16* g = &A[(size_t)(row0 + w * (TM / 4) + i * 16 + dr) * KD + k0 + dc];
                    __builtin_amdgcn_global_load_lds((const GAS void*)g, (LAS void*)&As[w * (TM / 4) + i * 16][0],
                                                     16, 0, 0);
                }
            } else if (TM == 128) {
                const int sr = t >> 1, sk = (t & 1) * 16;
                const __bf16* ap = &A[(size_t)(row0 + sr) * KD + k0 + sk];
                bf16x8 r0 = *(const bf16x8*)ap;
                bf16x8 r1 = *(const bf16x8*)(ap + 8);
                const int cb = (k0 + sk) & 255;
                #pragma unroll
                for (int j = 0; j < 8; ++j) {
                    r0[j] = (__bf16)fmaxf((float)r0[j] * scs[cb + j] + shs[cb + j], 0.f);
                    r1[j] = (__bf16)fmaxf((float)r1[j] * scs[cb + 8 + j] + shs[cb + 8 + j], 0.f);
                }
                *(bf16x8*)&As[sr][sk] = r0;
                *(bf16x8*)&As[sr][sk + 8] = r1;
            } else {
                const int sr = t >> 2, sk = (t & 3) * 8;
                bf16x8 r0 = *(const bf16x8*)&A[(size_t)(row0 + sr) * KD + k0 + sk];
                const int cb = (k0 + sk) & 255;
                #pragma unroll
                for (int j = 0; j < 8; ++j) r0[j] = (__bf16)fmaxf((float)r0[j] * scs[cb + j] + shs[cb + j], 0.f);
                *(bf16x8*)&As[sr][sk] = r0;
            }
            __syncthreads();
            bf16x8 af[MI], bfr[4];
            #pragma unroll
            for (int i = 0; i < MI; ++i) af[i] = *(const bf16x8*)&As[wm * (TM / 2) + i * 16 + l15][quad * 8];
            #pragma unroll
            for (int j = 0; j < 4; ++j) bfr[j] = *(const bf16x8*)&Bs[wn * 64 + j * 16 + l15][quad * 8];
            #pragma unroll
            for (int i = 0; i < MI; ++i)
                #pragma unroll
                for (int j = 0; j < 4; ++j)
                    acc[i][j] = __builtin_amdgcn_mfma_f32_16x16x32_bf16(af[i], bfr[j], acc[i][j], 0, 0, 0);
        }
    }
    __syncthreads();
    if constexpr (MODE == 0) {
        float* lsum = (float*)&As[0][0];  // [0..127]=sum, [128..255]=sumsq of block cols
        lsum[t] = 0.f;
        __syncthreads();
        #pragma unroll
        for (int j = 0; j < 4; ++j) {
            const int cb = wn * 64 + j * 16 + l15;
            const int col = c0 + cb;
            const float b = (float)bias[col];
            float s = 0.f, q = 0.f;
            #pragma unroll
            for (int i = 0; i < MI; ++i) {
                const size_t rbase = (size_t)(row0 + wm * (TM / 2) + i * 16 + quad * 4) * HD + col;
                #pragma unroll
                for (int r = 0; r < 4; ++r) {
                    float y = acc[i][j][r] + b;
                    O[rbase + (size_t)r * HD] = (__bf16)y;
                    s += y;
                    q += y * y;
                }
            }
            s += __shfl_xor(s, 16, 64); s += __shfl_xor(s, 32, 64);
            q += __shfl_xor(q, 16, 64); q += __shfl_xor(q, 32, 64);
            if (quad == 0) {
                atomicAdd(&lsum[cb], s);
                atomicAdd(&lsum[128 + cb], q);
            }
        }
        __syncthreads();
        if (t < 128) atomicAdd(&colsum[c0 + t], lsum[t]);
        else atomicAdd(&colsum[256 + c0 + t - 128], lsum[t]);
    } else {
        float bj[4], wj[4];
        #pragma unroll
        for (int j = 0; j < 4; ++j) {
            const int col = c0 + wn * 64 + j * 16 + l15;
            bj[j] = (float)bias[col];
            wj[j] = (float)W1b[col];
        }
        #pragma unroll
        for (int i = 0; i < MI; ++i) {
            #pragma unroll
            for (int r = 0; r < 4; ++r) {
                float p = 0.f;
                #pragma unroll
                for (int j = 0; j < 4; ++j) p += fmaxf(acc[i][j][r] + bj[j], 0.f) * wj[j];
                p += __shfl_xor(p, 1, 64); p += __shfl_xor(p, 2, 64);
                p += __shfl_xor(p, 4, 64); p += __shfl_xor(p, 8, 64);
                if (l15 == 0) atomicAdd(&x2[row0 + wm * (TM / 2) + i * 16 + quad * 4 + r], p);
            }
        }
    }
}

// ---------------- fused tail: +b1b, final BN+relu, mlp2 (one block per batch row) ----------------

__global__ __launch_bounds__(256) void k_mlp2(const float* __restrict__ x2, const __bf16* __restrict__ b1b,
                                              const __bf16* __restrict__ gf, const __bf16* __restrict__ bf_,
                                              const __bf16* __restrict__ W2a, const __bf16* __restrict__ b2a,
                                              const __bf16* __restrict__ W2b, const __bf16* __restrict__ b2b,
                                              const int* __restrict__ flags, void* __restrict__ out) {
    __shared__ float row[HD];
    __shared__ float hbuf[HD];
    __shared__ float part[256];
    const int b = blockIdx.x, t = threadIdx.x;
    const float b1 = (float)b1b[0];
    float s = 0.f, q = 0.f, mine = 0.f;
    #pragma unroll
    for (int r = 0; r < 32; ++r) {
        float v = x2[r * HD + t] + b1;
        s += v; q += v * v;
        if (r == b) mine = v;
    }
    float m = s * (1.0f / 32.0f);
    float var = fmaxf(q * (1.0f / 32.0f) - m * m, 0.f);
    float rs = rsqrtf(var + 1e-5f);
    float sc = (float)gf[t] * rs;
    float sh = (float)bf_[t] - m * sc;
    row[t] = fmaxf(mine * sc + sh, 0.f);
    __syncthreads();
    float acc = (float)b2a[t];
    for (int j = 0; j < HD; ++j) acc += row[j] * (float)W2a[j * HD + t];
    hbuf[t] = fmaxf(acc, 0.f);
    __syncthreads();
    const int k = t & 15, g = t >> 4;
    float p = 0.f;
    #pragma unroll
    for (int jj = 0; jj < 16; ++jj) p += hbuf[g * 16 + jj] * (float)W2b[(g * 16 + jj) * 16 + k];
    part[t] = p;
    __syncthreads();
    if (t < 16) {
        float o = (float)b2b[t];
        #pragma unroll
        for (int g2 = 0; g2 < 16; ++g2) o += part[g2 * 16 + t];
        if (flags[0]) ((__bf16*)out)[b * 16 + t] = (__bf16)o;
        else ((float*)out)[b * 16 + t] = o;
    }
}

// ---------------- launcher ----------------

extern "C" void kernel_launch(void* const* d_in, const int* in_sizes, int n_in,
                              void* d_out, int out_size, void* d_ws, size_t ws_size,
                              hipStream_t stream) {
    const int* ei = (const int*)d_in[4];

    char* ws = (char*)d_ws;
    size_t off_ = 0;
    auto ALLOC = [&](size_t b) { char* p = ws + off_; off_ += (b + 255) & ~(size_t)255; return p; };
    int* flags_ = (int*)ALLOC(8);
    int* deg_ = (int*)ALLOC(NN * 4);  // deg + cursor zeroed by one memset
    int* cursor_ = (int*)ALLOC(NN * 4);
    int* offs_ = (int*)ALLOC((NN + 1) * 4);
    float* invd_ = (float*)ALLOC(NN * 4);
    float* colsum_ = (float*)ALLOC(4 * 512 * 4);  // stats slot l for conv layer l; + x2 one memset
    float* x2_ = (float*)ALLOC(8192 * 4);
    int* csr_ = (int*)ALLOC((size_t)NE * 4);
    __bf16* blob_ = (__bf16*)ALLOC((size_t)TOTP * 2);
    __bf16* M_ = (__bf16*)ALLOC((size_t)NN * HD * 2);
    __bf16* Xa_ = (__bf16*)ALLOC((size_t)NN * HD * 2);
    __bf16* Xb_ = (__bf16*)ALLOC((size_t)NN * HD * 2);  // first 8 MB doubles as X0c
    __bf16* X0c_ = Xb_;  // dead before layer-1 GEMM writes Xb

    // converted parameter views (GEMM weights transposed to [out][in])
    __bf16* Wl0T = blob_ + 0;
    __bf16* Wr0T = blob_ + 32768;
    __bf16* bb0c = blob_ + 65536;
    __bf16* WlT = blob_ + 65792;
    __bf16* WrT = blob_ + 262400;
    __bf16* bbc = blob_ + 459008;
    __bf16* gammac = blob_ + 459776;
    __bf16* betac = blob_ + 460800;
    __bf16* W1aT = blob_ + 461824;
    __bf16* b1ac = blob_ + 723968;
    __bf16* W1bc = blob_ + 724224;
    __bf16* b1bc = blob_ + 724480;
    __bf16* gfc = blob_ + 724481;
    __bf16* bfc = blob_ + 724737;
    __bf16* W2ac = blob_ + 724993;
    __bf16* b2ac = blob_ + 790529;
    __bf16* W2bc = blob_ + 790785;
    __bf16* b2bc = blob_ + 794881;

    PtrTable pt;
    pt.p[0] = d_in[5];  pt.p[1] = d_in[6];  pt.p[2] = d_in[7];  pt.p[3] = d_in[8];
    pt.p[4] = d_in[9];  pt.p[5] = d_in[10]; pt.p[6] = d_in[11]; pt.p[7] = d_in[12];
    pt.p[8] = d_in[13]; pt.p[9] = d_in[14]; pt.p[10] = d_in[15]; pt.p[11] = d_in[16];
    pt.p[12] = d_in[17]; pt.p[13] = d_in[18]; pt.p[14] = d_in[19]; pt.p[15] = d_in[20];
    pt.p[16] = d_in[21]; pt.p[17] = d_in[22];

    hipMemsetAsync(deg_, 0, 2 * NN * 4, stream);
    hipMemsetAsync(colsum_, 0, 4 * 512 * 4 + 8192 * 4, stream);
    k_pre<<<4625, 256, 0, stream>>>((const unsigned*)d_in[0], ei, pt, d_in[0], d_in[1], d_in[2], d_in[3],
                                    flags_, deg_, blob_, X0c_);
    k_scan<<<1, 1024, 0, stream>>>(deg_, offs_, invd_);
    k_fill<<<NE / 256, 256, 0, stream>>>(ei, flags_, offs_, cursor_, csr_);

    // layer 0 (K=128): raw inputs, full-DMA staging
    k_agg0<<<NN / 16, 256, 0, stream>>>(X0c_, csr_, offs_, invd_, M_);
    k_gemm<0, 0, 128><<<dim3(NN / 128, 2), 256, 0, stream>>>(M_, Wl0T, X0c_, Wr0T, bb0c, 128, Xa_, colsum_,
                                                             nullptr, nullptr, nullptr, nullptr, nullptr);

    // layers 1..3 (K=256): consume RAW Y of prev layer + its BN params (fused)
    __bf16* Yin = Xa_;
    __bf16* Yo = Xb_;
    for (int l = 0; l < 3; ++l) {
        const float* ps = colsum_ + l * 512;
        const __bf16* pg = gammac + l * HD;
        const __bf16* pb = betac + l * HD;
        float* cs = colsum_ + (l + 1) * 512;
        k_agg<<<NN / 8, 256, 0, stream>>>(Yin, csr_, offs_, invd_, ps, pg, pb, M_);
        k_gemm<0, 1, 128><<<dim3(NN / 128, 2), 256, 0, stream>>>(M_, WlT + (size_t)l * HD * HD, Yin,
                                                                 WrT + (size_t)l * HD * HD, bbc + l * HD, 256, Yo,
                                                                 cs, nullptr, nullptr, ps, pg, pb);
        __bf16* tmp = Yin; Yin = Yo; Yo = tmp;
    }
    // Yin = RAW layer-3 output; BN3 fused into mlp1 A-staging (flat view [8192,1024])

    k_gemm<1, 2, 64><<<dim3(8192 / 64, 2), 256, 0, stream>>>(Yin, W1aT, nullptr, nullptr, b1ac, 1024, nullptr,
                                                             nullptr, W1bc, x2_, colsum_ + 3 * 512,
                                                             gammac + 3 * HD, betac + 3 * HD);
    k_mlp2<<<32, 256, 0, stream>>>(x2_, b1bc, gfc, bfc, W2ac, b2ac, W2bc, b2bc, flags_, d_out);
}

// Round 8
// 484.643 us; speedup vs baseline: 1.5056x; 1.0324x over previous
//
#include <hip/hip_runtime.h>

#define NN 32768
#define NE 524288
#define HD 256
#define TOTP 794897

#define GAS __attribute__((address_space(1)))
#define LAS __attribute__((address_space(3)))

typedef __attribute__((ext_vector_type(8))) __bf16 bf16x8;
typedef __attribute__((ext_vector_type(4))) float f32x4;

__device__ __forceinline__ float ld_any(const void* p, int i, int isbf16) {
    return isbf16 ? (float)((const __bf16*)p)[i] : ((const float*)p)[i];
}

struct PtrTable { const void* p[18]; };

// ---------------- fused preprocessing: detect + cvt_params + cvt_x0 + deg ----------------

__global__ __launch_bounds__(256) void k_pre(const unsigned* __restrict__ xw, const int* __restrict__ ei,
                                             PtrTable pt, const void* __restrict__ p0, const void* __restrict__ p1,
                                             const void* __restrict__ p2, const void* __restrict__ p3,
                                             int* __restrict__ flags, int* __restrict__ deg,
                                             __bf16* __restrict__ blob, __bf16* __restrict__ X0c) {
    __shared__ int fl[2];
    const int t = threadIdx.x;
    if (t < 64) {
        unsigned L = xw[t] & 0xFFFFu;
        int e = (int)((L >> 7) & 0xFF);
        unsigned long long b = __ballot(e >= 90 && e <= 135);
        if (t == 0) fl[0] = (b == ~0ULL) ? 1 : 0;  // 1 => bf16 inputs
    } else if (t < 128) {
        int u = t - 64;
        unsigned long long b = __ballot(ei[2 * u + 1] != 0);
        if (t == 64) fl[1] = (b == 0ULL) ? 1 : 0;  // 1 => int64 edges
    }
    __syncthreads();
    const int f0 = fl[0], f1 = fl[1];
    const int blk = blockIdx.x;
    if (blk == 0 && t < 2) flags[t] = fl[t];
    if (blk < 2048) {
        int i0 = (blk * 256 + t) * 8;
        int n = i0 >> 7, f = i0 & 127;
        const void* src = (f < 32) ? p0 : (f < 64) ? p1 : (f < 96) ? p2 : p3;
        int si = n * 32 + (f & 31);
        bf16x8 o;
        #pragma unroll
        for (int j = 0; j < 8; ++j) o[j] = (__bf16)ld_any(src, si + j, f0);
        *(bf16x8*)&X0c[i0] = o;
    } else if (blk < 3601) {
        const int off[23] = {0, 32768, 65536, 65792, 131328, 196864, 262400, 327936, 393472,
                             459008, 459776, 460800, 461824, 723968, 724224, 724480, 724481,
                             724737, 724993, 790529, 790785, 794881, TOTP};
        const signed char pidx[22] = {0, 1, 2, 3, 3, 3, 4, 4, 4, 5, 6, 7, 8, 9, 10, 11, 12, 13, 14, 15, 16, 17};
        const int sbase[22] = {0, 0, 0, 0, 65536, 131072, 0, 65536, 131072, 0, 0, 0, 0, 0, 0, 0, 0, 0, 0, 0, 0, 0};
        const signed char lR[22] = {7, 7, -1, 8, 8, 8, 8, 8, 8, -1, -1, -1, 10, -1, -1, -1, -1, -1, -1, -1, -1, -1};
        const signed char lC[22] = {8, 8, 0, 8, 8, 8, 8, 8, 8, 0, 0, 0, 8, 0, 0, 0, 0, 0, 0, 0, 0, 0};
        int base = ((blk - 2048) * 256 + t) * 2;
        #pragma unroll
        for (int j = 0; j < 2; ++j) {
            int i = base + j;
            if (i >= TOTP) break;
            int s = 0;
            while (i >= off[s + 1]) ++s;
            int jj = i - off[s];
            int si;
            if (lR[s] >= 0) {
                int Rm = (1 << lR[s]) - 1;
                si = sbase[s] + ((jj & Rm) << lC[s]) + (jj >> lR[s]);  // transpose read
            } else {
                si = sbase[s] + jj;
            }
            blob[i] = (__bf16)ld_any(pt.p[pidx[s]], si, f0);
        }
    } else {
        int e0 = ((blk - 3601) * 256 + t) * 2;
        int d0 = f1 ? ei[2 * e0] : ei[e0];
        int d1 = f1 ? ei[2 * e0 + 2] : ei[e0 + 1];
        atomicAdd(&deg[d0], 1);
        atomicAdd(&deg[d1], 1);
    }
}

// ---------------- CSR scan + fill ----------------

__global__ __launch_bounds__(1024) void k_scan(const int* __restrict__ deg, int* __restrict__ offs,
                                               float* __restrict__ invd) {
    __shared__ int wsum[16];
    const int t = threadIdx.x, lane = t & 63, wid = t >> 6;
    const int4* d4 = (const int4*)deg;
    int s = 0;
    #pragma unroll
    for (int j = 0; j < 8; ++j) {
        int4 v = d4[t * 8 + j];
        s += v.x + v.y + v.z + v.w;
    }
    int incl = s;
    #pragma unroll
    for (int d = 1; d < 64; d <<= 1) {
        int y = __shfl_up(incl, d, 64);
        if (lane >= d) incl += y;
    }
    if (lane == 63) wsum[wid] = incl;
    __syncthreads();
    if (t < 16) {
        int v2 = wsum[t];
        int inc2 = v2;
        #pragma unroll
        for (int d = 1; d < 16; d <<= 1) {
            int y = __shfl_up(inc2, d, 64);
            if (t >= d) inc2 += y;
        }
        wsum[t] = inc2 - v2;  // exclusive over wave totals
    }
    __syncthreads();
    int run = (incl - s) + wsum[wid];
    #pragma unroll
    for (int j = 0; j < 8; ++j) {
        int4 v = d4[t * 8 + j];
        int base = t * 32 + j * 4;
        offs[base + 0] = run; invd[base + 0] = v.x ? 1.f / (float)v.x : 0.f; run += v.x;
        offs[base + 1] = run; invd[base + 1] = v.y ? 1.f / (float)v.y : 0.f; run += v.y;
        offs[base + 2] = run; invd[base + 2] = v.z ? 1.f / (float)v.z : 0.f; run += v.z;
        offs[base + 3] = run; invd[base + 3] = v.w ? 1.f / (float)v.w : 0.f; run += v.w;
    }
    if (t == 1023) offs[NN] = run;
}

__global__ __launch_bounds__(256) void k_fill(const int* __restrict__ ei, const int* __restrict__ flags,
                                              const int* __restrict__ offs, int* __restrict__ cursor,
                                              int* __restrict__ csr) {
    int e = blockIdx.x * 256 + threadIdx.x;
    int f = flags[1];
    int d = f ? ei[2 * e] : ei[e];
    int s = f ? ei[2 * NE + 2 * e] : ei[NE + e];
    int p = atomicAdd(&cursor[d], 1);
    csr[offs[d] + p] = s;
}

// ---------------- mean aggregation, feature-sliced for per-XCD L2 residency ----------------
// Slice = 64 feats => 4 MB table slice fits one XCD's L2. gridDim.y = slice;
// x-major dispatch keeps ~one slice hot at a time (perf heuristic only).
// 8 lanes per node x 8 edges unrolled => 8 independent 128B gathers in flight.

__global__ __launch_bounds__(256) void k_agg0(const __bf16* __restrict__ X, const int* __restrict__ csr,
                                              const int* __restrict__ offs, const float* __restrict__ invd,
                                              __bf16* __restrict__ M) {
    const int t = threadIdx.x;
    const int n = blockIdx.x * 32 + (t >> 3);
    const int fo = blockIdx.y * 64 + (t & 7) * 8;
    const int beg = offs[n], end = offs[n + 1];
    float a[8] = {};
    int e = beg;
    for (; e + 8 <= end; e += 8) {
        #pragma unroll
        for (int u = 0; u < 8; ++u) {
            bf16x8 v = *(const bf16x8*)&X[(size_t)csr[e + u] * 128 + fo];
            #pragma unroll
            for (int j = 0; j < 8; ++j) a[j] += (float)v[j];
        }
    }
    for (; e < end; ++e) {
        bf16x8 v = *(const bf16x8*)&X[(size_t)csr[e] * 128 + fo];
        #pragma unroll
        for (int j = 0; j < 8; ++j) a[j] += (float)v[j];
    }
    const float id = invd[n];
    bf16x8 o;
    #pragma unroll
    for (int j = 0; j < 8; ++j) o[j] = (__bf16)(a[j] * id);
    *(bf16x8*)&M[(size_t)n * 128 + fo] = o;
}

__global__ __launch_bounds__(256) void k_agg(const __bf16* __restrict__ X, const int* __restrict__ csr,
                                             const int* __restrict__ offs, const float* __restrict__ invd,
                                             __bf16* __restrict__ M) {
    const int t = threadIdx.x;
    const int n = blockIdx.x * 32 + (t >> 3);
    const int fo = blockIdx.y * 64 + (t & 7) * 8;
    const int beg = offs[n], end = offs[n + 1];
    float a[8] = {};
    int e = beg;
    for (; e + 8 <= end; e += 8) {
        #pragma unroll
        for (int u = 0; u < 8; ++u) {
            bf16x8 v = *(const bf16x8*)&X[(size_t)csr[e + u] * HD + fo];
            #pragma unroll
            for (int j = 0; j < 8; ++j) a[j] += (float)v[j];
        }
    }
    for (; e < end; ++e) {
        bf16x8 v = *(const bf16x8*)&X[(size_t)csr[e] * HD + fo];
        #pragma unroll
        for (int j = 0; j < 8; ++j) a[j] += (float)v[j];
    }
    const float id = invd[n];
    bf16x8 o;
    #pragma unroll
    for (int j = 0; j < 8; ++j) o[j] = (__bf16)(a[j] * id);
    *(bf16x8*)&M[(size_t)n * HD + fo] = o;
}

// ---------------- MFMA GEMM (m97-style full-DMA staging): Y = A1@W1 (+ A2@W2) + bias ----------------
// TM x 128 block tile, 4 waves 2x2, wave tile (TM/2)x64, 16x16x32 MFMA.
// MODE 0: write raw y bf16 + fp32 column sum/sumsq atomics.
// MODE 1: x2[row] += sum_col relu(y + bias) * W1b[col]; no O write.

template <int MODE, int TM>
__global__ __launch_bounds__(256) void k_gemm(const __bf16* __restrict__ A1, const __bf16* __restrict__ WT1,
                                              const __bf16* __restrict__ A2, const __bf16* __restrict__ WT2,
                                              const __bf16* __restrict__ bias, int KD,
                                              __bf16* __restrict__ O, float* __restrict__ colsum,
                                              const __bf16* __restrict__ W1b, float* __restrict__ x2) {
    constexpr int MI = TM / 32;  // m-frags per wave
    __shared__ __bf16 As[TM][32];
    __shared__ __bf16 Bs[128][32];
    const int t = threadIdx.x;
    const int lane = t & 63, w = t >> 6;
    const int wm = w >> 1, wn = w & 1;
    const int quad = lane >> 4, l15 = lane & 15;
    const int row0 = blockIdx.x * TM, c0 = blockIdx.y * 128;
    const int dr = lane >> 2, dc = (lane & 3) * 8;  // DMA lane map (16 rows x 32 cols / instr)
    f32x4 acc[MI][4] = {};
    const int npass = A2 ? 2 : 1;
    for (int pass = 0; pass < npass; ++pass) {
        const __bf16* __restrict__ A = pass ? A2 : A1;
        const __bf16* __restrict__ WT = pass ? WT2 : WT1;
        for (int k0 = 0; k0 < KD; k0 += 32) {
            __syncthreads();
            #pragma unroll
            for (int i = 0; i < 2; ++i) {
                const __bf16* g = &WT[(size_t)(c0 + w * 32 + i * 16 + dr) * KD + k0 + dc];
                __builtin_amdgcn_global_load_lds((const GAS void*)g, (LAS void*)&Bs[w * 32 + i * 16][0], 16, 0, 0);
            }
            #pragma unroll
            for (int i = 0; i < TM / 64; ++i) {
                const __bf16* g = &A[(size_t)(row0 + w * (TM / 4) + i * 16 + dr) * KD + k0 + dc];
                __builtin_amdgcn_global_load_lds((const GAS void*)g, (LAS void*)&As[w * (TM / 4) + i * 16][0],
                                                 16, 0, 0);
            }
            __syncthreads();
            bf16x8 af[MI], bfr[4];
            #pragma unroll
            for (int i = 0; i < MI; ++i) af[i] = *(const bf16x8*)&As[wm * (TM / 2) + i * 16 + l15][quad * 8];
            #pragma unroll
            for (int j = 0; j < 4; ++j) bfr[j] = *(const bf16x8*)&Bs[wn * 64 + j * 16 + l15][quad * 8];
            #pragma unroll
            for (int i = 0; i < MI; ++i)
                #pragma unroll
                for (int j = 0; j < 4; ++j)
                    acc[i][j] = __builtin_amdgcn_mfma_f32_16x16x32_bf16(af[i], bfr[j], acc[i][j], 0, 0, 0);
        }
    }
    __syncthreads();
    if constexpr (MODE == 0) {
        float* lsum = (float*)&As[0][0];  // [0..127]=sum, [128..255]=sumsq of block cols
        lsum[t] = 0.f;
        __syncthreads();
        #pragma unroll
        for (int j = 0; j < 4; ++j) {
            const int cb = wn * 64 + j * 16 + l15;
            const int col = c0 + cb;
            const float b = (float)bias[col];
            float s = 0.f, q = 0.f;
            #pragma unroll
            for (int i = 0; i < MI; ++i) {
                const size_t rbase = (size_t)(row0 + wm * (TM / 2) + i * 16 + quad * 4) * HD + col;
                #pragma unroll
                for (int r = 0; r < 4; ++r) {
                    float y = acc[i][j][r] + b;
                    O[rbase + (size_t)r * HD] = (__bf16)y;
                    s += y;
                    q += y * y;
                }
            }
            s += __shfl_xor(s, 16, 64); s += __shfl_xor(s, 32, 64);
            q += __shfl_xor(q, 16, 64); q += __shfl_xor(q, 32, 64);
            if (quad == 0) {
                atomicAdd(&lsum[cb], s);
                atomicAdd(&lsum[128 + cb], q);
            }
        }
        __syncthreads();
        if (t < 128) atomicAdd(&colsum[c0 + t], lsum[t]);
        else atomicAdd(&colsum[256 + c0 + t - 128], lsum[t]);
    } else {
        float bj[4], wj[4];
        #pragma unroll
        for (int j = 0; j < 4; ++j) {
            const int col = c0 + wn * 64 + j * 16 + l15;
            bj[j] = (float)bias[col];
            wj[j] = (float)W1b[col];
        }
        #pragma unroll
        for (int i = 0; i < MI; ++i) {
            #pragma unroll
            for (int r = 0; r < 4; ++r) {
                float p = 0.f;
                #pragma unroll
                for (int j = 0; j < 4; ++j) p += fmaxf(acc[i][j][r] + bj[j], 0.f) * wj[j];
                p += __shfl_xor(p, 1, 64); p += __shfl_xor(p, 2, 64);
                p += __shfl_xor(p, 4, 64); p += __shfl_xor(p, 8, 64);
                if (l15 == 0) atomicAdd(&x2[row0 + wm * (TM / 2) + i * 16 + quad * 4 + r], p);
            }
        }
    }
}

// ---------------- BN apply, in place: Y (raw bf16) -> relu(BN(Y)) ----------------

__global__ __launch_bounds__(256) void k_bnapply(__bf16* __restrict__ Y, const float* __restrict__ pstat,
                                                 const __bf16* __restrict__ gamma, const __bf16* __restrict__ beta) {
    __shared__ float sc[256], sh[256];
    const int t = threadIdx.x;
    {
        const float invn = 1.0f / NN;
        float m = pstat[t] * invn;
        float var = fmaxf(pstat[256 + t] * invn - m * m, 0.f);
        float rs = rsqrtf(var + 1e-5f);
        float s = (float)gamma[t] * rs;
        sc[t] = s;
        sh[t] = (float)beta[t] - m * s;
    }
    __syncthreads();
    size_t i = ((size_t)blockIdx.x * 256 + t) * 8;
    int c = (int)(i & 255);
    bf16x8 y = *(const bf16x8*)&Y[i];
    bf16x8 o;
    #pragma unroll
    for (int j = 0; j < 8; ++j) o[j] = (__bf16)fmaxf((float)y[j] * sc[c + j] + sh[c + j], 0.f);
    *(bf16x8*)&Y[i] = o;
}

// ---------------- fused tail: +b1b, final BN+relu, mlp2 (one block per batch row) ----------------

__global__ __launch_bounds__(256) void k_mlp2(const float* __restrict__ x2, const __bf16* __restrict__ b1b,
                                              const __bf16* __restrict__ gf, const __bf16* __restrict__ bf_,
                                              const __bf16* __restrict__ W2a, const __bf16* __restrict__ b2a,
                                              const __bf16* __restrict__ W2b, const __bf16* __restrict__ b2b,
                                              const int* __restrict__ flags, void* __restrict__ out) {
    __shared__ float row[HD];
    __shared__ float hbuf[HD];
    __shared__ float part[256];
    const int b = blockIdx.x, t = threadIdx.x;
    const float b1 = (float)b1b[0];
    float s = 0.f, q = 0.f, mine = 0.f;
    #pragma unroll
    for (int r = 0; r < 32; ++r) {
        float v = x2[r * HD + t] + b1;
        s += v; q += v * v;
        if (r == b) mine = v;
    }
    float m = s * (1.0f / 32.0f);
    float var = fmaxf(q * (1.0f / 32.0f) - m * m, 0.f);
    float rs = rsqrtf(var + 1e-5f);
    float sc = (float)gf[t] * rs;
    float sh = (float)bf_[t] - m * sc;
    row[t] = fmaxf(mine * sc + sh, 0.f);
    __syncthreads();
    float acc = (float)b2a[t];
    for (int j = 0; j < HD; ++j) acc += row[j] * (float)W2a[j * HD + t];
    hbuf[t] = fmaxf(acc, 0.f);
    __syncthreads();
    const int k = t & 15, g = t >> 4;
    float p = 0.f;
    #pragma unroll
    for (int jj = 0; jj < 16; ++jj) p += hbuf[g * 16 + jj] * (float)W2b[(g * 16 + jj) * 16 + k];
    part[t] = p;
    __syncthreads();
    if (t < 16) {
        float o = (float)b2b[t];
        #pragma unroll
        for (int g2 = 0; g2 < 16; ++g2) o += part[g2 * 16 + t];
        if (flags[0]) ((__bf16*)out)[b * 16 + t] = (__bf16)o;
        else ((float*)out)[b * 16 + t] = o;
    }
}

// ---------------- launcher ----------------

extern "C" void kernel_launch(void* const* d_in, const int* in_sizes, int n_in,
                              void* d_out, int out_size, void* d_ws, size_t ws_size,
                              hipStream_t stream) {
    const int* ei = (const int*)d_in[4];

    char* ws = (char*)d_ws;
    size_t off_ = 0;
    auto ALLOC = [&](size_t b) { char* p = ws + off_; off_ += (b + 255) & ~(size_t)255; return p; };
    int* flags_ = (int*)ALLOC(8);
    int* deg_ = (int*)ALLOC(NN * 4);  // deg + cursor zeroed by one memset
    int* cursor_ = (int*)ALLOC(NN * 4);
    int* offs_ = (int*)ALLOC((NN + 1) * 4);
    float* invd_ = (float*)ALLOC(NN * 4);
    float* colsum_ = (float*)ALLOC(4 * 512 * 4);  // stats slot l for conv layer l; + x2 one memset
    float* x2_ = (float*)ALLOC(8192 * 4);
    int* csr_ = (int*)ALLOC((size_t)NE * 4);
    __bf16* blob_ = (__bf16*)ALLOC((size_t)TOTP * 2);
    __bf16* M_ = (__bf16*)ALLOC((size_t)NN * HD * 2);
    __bf16* Xa_ = (__bf16*)ALLOC((size_t)NN * HD * 2);
    __bf16* Xb_ = (__bf16*)ALLOC((size_t)NN * HD * 2);  // first 8 MB doubles as X0c
    __bf16* X0c_ = Xb_;  // dead before layer-1 GEMM writes Xb

    // converted parameter views (GEMM weights transposed to [out][in])
    __bf16* Wl0T = blob_ + 0;
    __bf16* Wr0T = blob_ + 32768;
    __bf16* bb0c = blob_ + 65536;
    __bf16* WlT = blob_ + 65792;
    __bf16* WrT = blob_ + 262400;
    __bf16* bbc = blob_ + 459008;
    __bf16* gammac = blob_ + 459776;
    __bf16* betac = blob_ + 460800;
    __bf16* W1aT = blob_ + 461824;
    __bf16* b1ac = blob_ + 723968;
    __bf16* W1bc = blob_ + 724224;
    __bf16* b1bc = blob_ + 724480;
    __bf16* gfc = blob_ + 724481;
    __bf16* bfc = blob_ + 724737;
    __bf16* W2ac = blob_ + 724993;
    __bf16* b2ac = blob_ + 790529;
    __bf16* W2bc = blob_ + 790785;
    __bf16* b2bc = blob_ + 794881;

    PtrTable pt;
    pt.p[0] = d_in[5];  pt.p[1] = d_in[6];  pt.p[2] = d_in[7];  pt.p[3] = d_in[8];
    pt.p[4] = d_in[9];  pt.p[5] = d_in[10]; pt.p[6] = d_in[11]; pt.p[7] = d_in[12];
    pt.p[8] = d_in[13]; pt.p[9] = d_in[14]; pt.p[10] = d_in[15]; pt.p[11] = d_in[16];
    pt.p[12] = d_in[17]; pt.p[13] = d_in[18]; pt.p[14] = d_in[19]; pt.p[15] = d_in[20];
    pt.p[16] = d_in[21]; pt.p[17] = d_in[22];

    hipMemsetAsync(deg_, 0, 2 * NN * 4, stream);
    hipMemsetAsync(colsum_, 0, 4 * 512 * 4 + 8192 * 4, stream);
    k_pre<<<4625, 256, 0, stream>>>((const unsigned*)d_in[0], ei, pt, d_in[0], d_in[1], d_in[2], d_in[3],
                                    flags_, deg_, blob_, X0c_);
    k_scan<<<1, 1024, 0, stream>>>(deg_, offs_, invd_);
    k_fill<<<NE / 256, 256, 0, stream>>>(ei, flags_, offs_, cursor_, csr_);

    // layer 0 (K=128)
    k_agg0<<<dim3(NN / 32, 2), 256, 0, stream>>>(X0c_, csr_, offs_, invd_, M_);
    k_gemm<0, 128><<<dim3(NN / 128, 2), 256, 0, stream>>>(M_, Wl0T, X0c_, Wr0T, bb0c, 128, Xa_, colsum_,
                                                          nullptr, nullptr);
    k_bnapply<<<NN / 8, 256, 0, stream>>>(Xa_, colsum_, gammac, betac);

    // layers 1..3 (K=256): Xin is post-BN (materialized); GEMM full-DMA both operands
    __bf16* Xin = Xa_;
    __bf16* Xo = Xb_;
    for (int l = 0; l < 3; ++l) {
        float* cs = colsum_ + (l + 1) * 512;
        k_agg<<<dim3(NN / 32, 4), 256, 0, stream>>>(Xin, csr_, offs_, invd_, M_);
        k_gemm<0, 128><<<dim3(NN / 128, 2), 256, 0, stream>>>(M_, WlT + (size_t)l * HD * HD, Xin,
                                                              WrT + (size_t)l * HD * HD, bbc + l * HD, 256, Xo,
                                                              cs, nullptr, nullptr);
        k_bnapply<<<NN / 8, 256, 0, stream>>>(Xo, cs, gammac + (l + 1) * HD, betac + (l + 1) * HD);
        __bf16* tmp = Xin; Xin = Xo; Xo = tmp;
    }
    // Xin = post-BN layer-3 output, flat-viewed as [8192, 1024]

    k_gemm<1, 64><<<dim3(8192 / 64, 2), 256, 0, stream>>>(Xin, W1aT, nullptr, nullptr, b1ac, 1024, nullptr,
                                                          nullptr, W1bc, x2_);
    k_mlp2<<<32, 256, 0, stream>>>(x2_, b1bc, gfc, bfc, W2ac, b2ac, W2bc, b2bc, flags_, d_out);
}

// Round 9
// 449.270 us; speedup vs baseline: 1.6242x; 1.0787x over previous
//
#include <hip/hip_runtime.h>

#define NN 32768
#define NE 524288
#define HD 256
#define TOTP 794897

#define GAS __attribute__((address_space(1)))
#define LAS __attribute__((address_space(3)))

typedef __attribute__((ext_vector_type(8))) __bf16 bf16x8;
typedef __attribute__((ext_vector_type(4))) float f32x4;

__device__ __forceinline__ float ld_any(const void* p, int i, int isbf16) {
    return isbf16 ? (float)((const __bf16*)p)[i] : ((const float*)p)[i];
}

struct PtrTable { const void* p[18]; };

// ---------------- fused preprocessing: detect + cvt_params + cvt_x0 + deg ----------------

__global__ __launch_bounds__(256) void k_pre(const unsigned* __restrict__ xw, const int* __restrict__ ei,
                                             PtrTable pt, const void* __restrict__ p0, const void* __restrict__ p1,
                                             const void* __restrict__ p2, const void* __restrict__ p3,
                                             int* __restrict__ flags, int* __restrict__ deg,
                                             __bf16* __restrict__ blob, __bf16* __restrict__ X0c) {
    __shared__ int fl[2];
    const int t = threadIdx.x;
    if (t < 64) {
        unsigned L = xw[t] & 0xFFFFu;
        int e = (int)((L >> 7) & 0xFF);
        unsigned long long b = __ballot(e >= 90 && e <= 135);
        if (t == 0) fl[0] = (b == ~0ULL) ? 1 : 0;  // 1 => bf16 inputs
    } else if (t < 128) {
        int u = t - 64;
        unsigned long long b = __ballot(ei[2 * u + 1] != 0);
        if (t == 64) fl[1] = (b == 0ULL) ? 1 : 0;  // 1 => int64 edges
    }
    __syncthreads();
    const int f0 = fl[0], f1 = fl[1];
    const int blk = blockIdx.x;
    if (blk == 0 && t < 2) flags[t] = fl[t];
    if (blk < 2048) {
        int i0 = (blk * 256 + t) * 8;
        int n = i0 >> 7, f = i0 & 127;
        const void* src = (f < 32) ? p0 : (f < 64) ? p1 : (f < 96) ? p2 : p3;
        int si = n * 32 + (f & 31);
        bf16x8 o;
        #pragma unroll
        for (int j = 0; j < 8; ++j) o[j] = (__bf16)ld_any(src, si + j, f0);
        *(bf16x8*)&X0c[i0] = o;
    } else if (blk < 3601) {
        const int off[23] = {0, 32768, 65536, 65792, 131328, 196864, 262400, 327936, 393472,
                             459008, 459776, 460800, 461824, 723968, 724224, 724480, 724481,
                             724737, 724993, 790529, 790785, 794881, TOTP};
        const signed char pidx[22] = {0, 1, 2, 3, 3, 3, 4, 4, 4, 5, 6, 7, 8, 9, 10, 11, 12, 13, 14, 15, 16, 17};
        const int sbase[22] = {0, 0, 0, 0, 65536, 131072, 0, 65536, 131072, 0, 0, 0, 0, 0, 0, 0, 0, 0, 0, 0, 0, 0};
        const signed char lR[22] = {7, 7, -1, 8, 8, 8, 8, 8, 8, -1, -1, -1, 10, -1, -1, -1, -1, -1, -1, -1, -1, -1};
        const signed char lC[22] = {8, 8, 0, 8, 8, 8, 8, 8, 8, 0, 0, 0, 8, 0, 0, 0, 0, 0, 0, 0, 0, 0};
        int base = ((blk - 2048) * 256 + t) * 2;
        #pragma unroll
        for (int j = 0; j < 2; ++j) {
            int i = base + j;
            if (i >= TOTP) break;
            int s = 0;
            while (i >= off[s + 1]) ++s;
            int jj = i - off[s];
            int si;
            if (lR[s] >= 0) {
                int Rm = (1 << lR[s]) - 1;
                si = sbase[s] + ((jj & Rm) << lC[s]) + (jj >> lR[s]);  // transpose read
            } else {
                si = sbase[s] + jj;
            }
            blob[i] = (__bf16)ld_any(pt.p[pidx[s]], si, f0);
        }
    } else {
        int e0 = ((blk - 3601) * 256 + t) * 2;
        int d0 = f1 ? ei[2 * e0] : ei[e0];
        int d1 = f1 ? ei[2 * e0 + 2] : ei[e0 + 1];
        atomicAdd(&deg[d0], 1);
        atomicAdd(&deg[d1], 1);
    }
}

// ---------------- CSR region allocation (replaces single-block scan) ----------------
// Region order is irrelevant (within-node edge order is already nondeterministic
// via k_fill's atomic cursor), so: wave-local prefix + one atomicAdd per wave.
// Coalesced reads/writes, 128 blocks — vs the old 1-block uncoalesced scan (44.5us).

__global__ __launch_bounds__(256) void k_alloc(const int* __restrict__ deg, int* __restrict__ gcur,
                                               int* __restrict__ offs, float* __restrict__ invd) {
    const int n = blockIdx.x * 256 + threadIdx.x;
    const int lane = threadIdx.x & 63;
    const int v = deg[n];
    invd[n] = v ? 1.f / (float)v : 0.f;
    int incl = v;
    #pragma unroll
    for (int d = 1; d < 64; d <<= 1) {
        int y = __shfl_up(incl, d, 64);
        if (lane >= d) incl += y;
    }
    int base = 0;
    if (lane == 63) base = atomicAdd(gcur, incl);
    base = __shfl(base, 63, 64);
    offs[n] = base + incl - v;
}

__global__ __launch_bounds__(256) void k_fill(const int* __restrict__ ei, const int* __restrict__ flags,
                                              const int* __restrict__ offs, int* __restrict__ cursor,
                                              int* __restrict__ csr) {
    int e = blockIdx.x * 256 + threadIdx.x;
    int f = flags[1];
    int d = f ? ei[2 * e] : ei[e];
    int s = f ? ei[2 * NE + 2 * e] : ei[NE + e];
    int p = atomicAdd(&cursor[d], 1);
    csr[offs[d] + p] = s;
}

// ---------------- mean aggregation, feature-sliced for per-XCD L2 residency ----------------

__global__ __launch_bounds__(256) void k_agg0(const __bf16* __restrict__ X, const int* __restrict__ csr,
                                              const int* __restrict__ offs, const int* __restrict__ deg,
                                              const float* __restrict__ invd, __bf16* __restrict__ M) {
    const int t = threadIdx.x;
    const int n = blockIdx.x * 32 + (t >> 3);
    const int fo = blockIdx.y * 64 + (t & 7) * 8;
    const int beg = offs[n], end = beg + deg[n];
    float a[8] = {};
    int e = beg;
    for (; e + 8 <= end; e += 8) {
        #pragma unroll
        for (int u = 0; u < 8; ++u) {
            bf16x8 v = *(const bf16x8*)&X[(size_t)csr[e + u] * 128 + fo];
            #pragma unroll
            for (int j = 0; j < 8; ++j) a[j] += (float)v[j];
        }
    }
    for (; e < end; ++e) {
        bf16x8 v = *(const bf16x8*)&X[(size_t)csr[e] * 128 + fo];
        #pragma unroll
        for (int j = 0; j < 8; ++j) a[j] += (float)v[j];
    }
    const float id = invd[n];
    bf16x8 o;
    #pragma unroll
    for (int j = 0; j < 8; ++j) o[j] = (__bf16)(a[j] * id);
    *(bf16x8*)&M[(size_t)n * 128 + fo] = o;
}

__global__ __launch_bounds__(256) void k_agg(const __bf16* __restrict__ X, const int* __restrict__ csr,
                                             const int* __restrict__ offs, const int* __restrict__ deg,
                                             const float* __restrict__ invd, __bf16* __restrict__ M) {
    const int t = threadIdx.x;
    const int n = blockIdx.x * 32 + (t >> 3);
    const int fo = blockIdx.y * 64 + (t & 7) * 8;
    const int beg = offs[n], end = beg + deg[n];
    float a[8] = {};
    int e = beg;
    for (; e + 8 <= end; e += 8) {
        #pragma unroll
        for (int u = 0; u < 8; ++u) {
            bf16x8 v = *(const bf16x8*)&X[(size_t)csr[e + u] * HD + fo];
            #pragma unroll
            for (int j = 0; j < 8; ++j) a[j] += (float)v[j];
        }
    }
    for (; e < end; ++e) {
        bf16x8 v = *(const bf16x8*)&X[(size_t)csr[e] * HD + fo];
        #pragma unroll
        for (int j = 0; j < 8; ++j) a[j] += (float)v[j];
    }
    const float id = invd[n];
    bf16x8 o;
    #pragma unroll
    for (int j = 0; j < 8; ++j) o[j] = (__bf16)(a[j] * id);
    *(bf16x8*)&M[(size_t)n * HD + fo] = o;
}

// ---------------- MFMA GEMM (full-DMA staging): Y = A1@W1 (+ A2@W2) + bias ----------------

template <int MODE, int TM>
__global__ __launch_bounds__(256) void k_gemm(const __bf16* __restrict__ A1, const __bf16* __restrict__ WT1,
                                              const __bf16* __restrict__ A2, const __bf16* __restrict__ WT2,
                                              const __bf16* __restrict__ bias, int KD,
                                              __bf16* __restrict__ O, float* __restrict__ colsum,
                                              const __bf16* __restrict__ W1b, float* __restrict__ x2) {
    constexpr int MI = TM / 32;
    __shared__ __bf16 As[TM][32];
    __shared__ __bf16 Bs[128][32];
    const int t = threadIdx.x;
    const int lane = t & 63, w = t >> 6;
    const int wm = w >> 1, wn = w & 1;
    const int quad = lane >> 4, l15 = lane & 15;
    const int row0 = blockIdx.x * TM, c0 = blockIdx.y * 128;
    const int dr = lane >> 2, dc = (lane & 3) * 8;
    f32x4 acc[MI][4] = {};
    const int npass = A2 ? 2 : 1;
    for (int pass = 0; pass < npass; ++pass) {
        const __bf16* __restrict__ A = pass ? A2 : A1;
        const __bf16* __restrict__ WT = pass ? WT2 : WT1;
        for (int k0 = 0; k0 < KD; k0 += 32) {
            __syncthreads();
            #pragma unroll
            for (int i = 0; i < 2; ++i) {
                const __bf16* g = &WT[(size_t)(c0 + w * 32 + i * 16 + dr) * KD + k0 + dc];
                __builtin_amdgcn_global_load_lds((const GAS void*)g, (LAS void*)&Bs[w * 32 + i * 16][0], 16, 0, 0);
            }
            #pragma unroll
            for (int i = 0; i < TM / 64; ++i) {
                const __bf16* g = &A[(size_t)(row0 + w * (TM / 4) + i * 16 + dr) * KD + k0 + dc];
                __builtin_amdgcn_global_load_lds((const GAS void*)g, (LAS void*)&As[w * (TM / 4) + i * 16][0],
                                                 16, 0, 0);
            }
            __syncthreads();
            bf16x8 af[MI], bfr[4];
            #pragma unroll
            for (int i = 0; i < MI; ++i) af[i] = *(const bf16x8*)&As[wm * (TM / 2) + i * 16 + l15][quad * 8];
            #pragma unroll
            for (int j = 0; j < 4; ++j) bfr[j] = *(const bf16x8*)&Bs[wn * 64 + j * 16 + l15][quad * 8];
            #pragma unroll
            for (int i = 0; i < MI; ++i)
                #pragma unroll
                for (int j = 0; j < 4; ++j)
                    acc[i][j] = __builtin_amdgcn_mfma_f32_16x16x32_bf16(af[i], bfr[j], acc[i][j], 0, 0, 0);
        }
    }
    __syncthreads();
    if constexpr (MODE == 0) {
        float* lsum = (float*)&As[0][0];
        lsum[t] = 0.f;
        __syncthreads();
        #pragma unroll
        for (int j = 0; j < 4; ++j) {
            const int cb = wn * 64 + j * 16 + l15;
            const int col = c0 + cb;
            const float b = (float)bias[col];
            float s = 0.f, q = 0.f;
            #pragma unroll
            for (int i = 0; i < MI; ++i) {
                const size_t rbase = (size_t)(row0 + wm * (TM / 2) + i * 16 + quad * 4) * HD + col;
                #pragma unroll
                for (int r = 0; r < 4; ++r) {
                    float y = acc[i][j][r] + b;
                    O[rbase + (size_t)r * HD] = (__bf16)y;
                    s += y;
                    q += y * y;
                }
            }
            s += __shfl_xor(s, 16, 64); s += __shfl_xor(s, 32, 64);
            q += __shfl_xor(q, 16, 64); q += __shfl_xor(q, 32, 64);
            if (quad == 0) {
                atomicAdd(&lsum[cb], s);
                atomicAdd(&lsum[128 + cb], q);
            }
        }
        __syncthreads();
        if (t < 128) atomicAdd(&colsum[c0 + t], lsum[t]);
        else atomicAdd(&colsum[256 + c0 + t - 128], lsum[t]);
    } else {
        float bj[4], wj[4];
        #pragma unroll
        for (int j = 0; j < 4; ++j) {
            const int col = c0 + wn * 64 + j * 16 + l15;
            bj[j] = (float)bias[col];
            wj[j] = (float)W1b[col];
        }
        #pragma unroll
        for (int i = 0; i < MI; ++i) {
            #pragma unroll
            for (int r = 0; r < 4; ++r) {
                float p = 0.f;
                #pragma unroll
                for (int j = 0; j < 4; ++j) p += fmaxf(acc[i][j][r] + bj[j], 0.f) * wj[j];
                p += __shfl_xor(p, 1, 64); p += __shfl_xor(p, 2, 64);
                p += __shfl_xor(p, 4, 64); p += __shfl_xor(p, 8, 64);
                if (l15 == 0) atomicAdd(&x2[row0 + wm * (TM / 2) + i * 16 + quad * 4 + r], p);
            }
        }
    }
}

// ---------------- BN apply, in place: Y (raw bf16) -> relu(BN(Y)) ----------------

__global__ __launch_bounds__(256) void k_bnapply(__bf16* __restrict__ Y, const float* __restrict__ pstat,
                                                 const __bf16* __restrict__ gamma, const __bf16* __restrict__ beta) {
    __shared__ float sc[256], sh[256];
    const int t = threadIdx.x;
    {
        const float invn = 1.0f / NN;
        float m = pstat[t] * invn;
        float var = fmaxf(pstat[256 + t] * invn - m * m, 0.f);
        float rs = rsqrtf(var + 1e-5f);
        float s = (float)gamma[t] * rs;
        sc[t] = s;
        sh[t] = (float)beta[t] - m * s;
    }
    __syncthreads();
    size_t i = ((size_t)blockIdx.x * 256 + t) * 8;
    int c = (int)(i & 255);
    bf16x8 y = *(const bf16x8*)&Y[i];
    bf16x8 o;
    #pragma unroll
    for (int j = 0; j < 8; ++j) o[j] = (__bf16)fmaxf((float)y[j] * sc[c + j] + sh[c + j], 0.f);
    *(bf16x8*)&Y[i] = o;
}

// ---------------- fused tail: +b1b, final BN+relu, mlp2 (one block per batch row) ----------------

__global__ __launch_bounds__(256) void k_mlp2(const float* __restrict__ x2, const __bf16* __restrict__ b1b,
                                              const __bf16* __restrict__ gf, const __bf16* __restrict__ bf_,
                                              const __bf16* __restrict__ W2a, const __bf16* __restrict__ b2a,
                                              const __bf16* __restrict__ W2b, const __bf16* __restrict__ b2b,
                                              const int* __restrict__ flags, void* __restrict__ out) {
    __shared__ float row[HD];
    __shared__ float hbuf[HD];
    __shared__ float part[256];
    const int b = blockIdx.x, t = threadIdx.x;
    const float b1 = (float)b1b[0];
    float s = 0.f, q = 0.f, mine = 0.f;
    #pragma unroll
    for (int r = 0; r < 32; ++r) {
        float v = x2[r * HD + t] + b1;
        s += v; q += v * v;
        if (r == b) mine = v;
    }
    float m = s * (1.0f / 32.0f);
    float var = fmaxf(q * (1.0f / 32.0f) - m * m, 0.f);
    float rs = rsqrtf(var + 1e-5f);
    float sc = (float)gf[t] * rs;
    float sh = (float)bf_[t] - m * sc;
    row[t] = fmaxf(mine * sc + sh, 0.f);
    __syncthreads();
    float acc = (float)b2a[t];
    for (int j = 0; j < HD; ++j) acc += row[j] * (float)W2a[j * HD + t];
    hbuf[t] = fmaxf(acc, 0.f);
    __syncthreads();
    const int k = t & 15, g = t >> 4;
    float p = 0.f;
    #pragma unroll
    for (int jj = 0; jj < 16; ++jj) p += hbuf[g * 16 + jj] * (float)W2b[(g * 16 + jj) * 16 + k];
    part[t] = p;
    __syncthreads();
    if (t < 16) {
        float o = (float)b2b[t];
        #pragma unroll
        for (int g2 = 0; g2 < 16; ++g2) o += part[g2 * 16 + t];
        if (flags[0]) ((__bf16*)out)[b * 16 + t] = (__bf16)o;
        else ((float*)out)[b * 16 + t] = o;
    }
}

// ---------------- launcher ----------------

extern "C" void kernel_launch(void* const* d_in, const int* in_sizes, int n_in,
                              void* d_out, int out_size, void* d_ws, size_t ws_size,
                              hipStream_t stream) {
    const int* ei = (const int*)d_in[4];

    char* ws = (char*)d_ws;
    size_t off_ = 0;
    auto ALLOC = [&](size_t b) { char* p = ws + off_; off_ += (b + 255) & ~(size_t)255; return p; };
    int* flags_ = (int*)ALLOC(8);
    int* deg_ = (int*)ALLOC(NN * 4);  // deg + cursor zeroed by one memset
    int* cursor_ = (int*)ALLOC(NN * 4);
    int* offs_ = (int*)ALLOC(NN * 4);
    float* invd_ = (float*)ALLOC(NN * 4);
    float* colsum_ = (float*)ALLOC(4 * 512 * 4);  // stats slot l; + x2 + gcur: one memset
    float* x2_ = (float*)ALLOC(8192 * 4);
    int* gcur_ = (int*)ALLOC(4);
    int* csr_ = (int*)ALLOC((size_t)NE * 4);
    __bf16* blob_ = (__bf16*)ALLOC((size_t)TOTP * 2);
    __bf16* M_ = (__bf16*)ALLOC((size_t)NN * HD * 2);
    __bf16* Xa_ = (__bf16*)ALLOC((size_t)NN * HD * 2);
    __bf16* Xb_ = (__bf16*)ALLOC((size_t)NN * HD * 2);  // first 8 MB doubles as X0c
    __bf16* X0c_ = Xb_;  // dead before layer-1 GEMM writes Xb

    __bf16* Wl0T = blob_ + 0;
    __bf16* Wr0T = blob_ + 32768;
    __bf16* bb0c = blob_ + 65536;
    __bf16* WlT = blob_ + 65792;
    __bf16* WrT = blob_ + 262400;
    __bf16* bbc = blob_ + 459008;
    __bf16* gammac = blob_ + 459776;
    __bf16* betac = blob_ + 460800;
    __bf16* W1aT = blob_ + 461824;
    __bf16* b1ac = blob_ + 723968;
    __bf16* W1bc = blob_ + 724224;
    __bf16* b1bc = blob_ + 724480;
    __bf16* gfc = blob_ + 724481;
    __bf16* bfc = blob_ + 724737;
    __bf16* W2ac = blob_ + 724993;
    __bf16* b2ac = blob_ + 790529;
    __bf16* W2bc = blob_ + 790785;
    __bf16* b2bc = blob_ + 794881;

    PtrTable pt;
    pt.p[0] = d_in[5];  pt.p[1] = d_in[6];  pt.p[2] = d_in[7];  pt.p[3] = d_in[8];
    pt.p[4] = d_in[9];  pt.p[5] = d_in[10]; pt.p[6] = d_in[11]; pt.p[7] = d_in[12];
    pt.p[8] = d_in[13]; pt.p[9] = d_in[14]; pt.p[10] = d_in[15]; pt.p[11] = d_in[16];
    pt.p[12] = d_in[17]; pt.p[13] = d_in[18]; pt.p[14] = d_in[19]; pt.p[15] = d_in[20];
    pt.p[16] = d_in[21]; pt.p[17] = d_in[22];

    hipMemsetAsync(deg_, 0, 2 * NN * 4, stream);                       // deg + cursor
    hipMemsetAsync(colsum_, 0, 4 * 512 * 4 + 8192 * 4 + 256, stream);  // stats + x2 + gcur
    k_pre<<<4625, 256, 0, stream>>>((const unsigned*)d_in[0], ei, pt, d_in[0], d_in[1], d_in[2], d_in[3],
                                    flags_, deg_, blob_, X0c_);
    k_alloc<<<NN / 256, 256, 0, stream>>>(deg_, gcur_, offs_, invd_);
    k_fill<<<NE / 256, 256, 0, stream>>>(ei, flags_, offs_, cursor_, csr_);

    // layer 0 (K=128)
    k_agg0<<<dim3(NN / 32, 2), 256, 0, stream>>>(X0c_, csr_, offs_, deg_, invd_, M_);
    k_gemm<0, 128><<<dim3(NN / 128, 2), 256, 0, stream>>>(M_, Wl0T, X0c_, Wr0T, bb0c, 128, Xa_, colsum_,
                                                          nullptr, nullptr);
    k_bnapply<<<NN / 8, 256, 0, stream>>>(Xa_, colsum_, gammac, betac);

    // layers 1..3 (K=256)
    __bf16* Xin = Xa_;
    __bf16* Xo = Xb_;
    for (int l = 0; l < 3; ++l) {
        float* cs = colsum_ + (l + 1) * 512;
        k_agg<<<dim3(NN / 32, 4), 256, 0, stream>>>(Xin, csr_, offs_, deg_, invd_, M_);
        k_gemm<0, 128><<<dim3(NN / 128, 2), 256, 0, stream>>>(M_, WlT + (size_t)l * HD * HD, Xin,
                                                              WrT + (size_t)l * HD * HD, bbc + l * HD, 256, Xo,
                                                              cs, nullptr, nullptr);
        k_bnapply<<<NN / 8, 256, 0, stream>>>(Xo, cs, gammac + (l + 1) * HD, betac + (l + 1) * HD);
        __bf16* tmp = Xin; Xin = Xo; Xo = tmp;
    }
    // Xin = post-BN layer-3 output, flat-viewed as [8192, 1024]

    k_gemm<1, 64><<<dim3(8192 / 64, 2), 256, 0, stream>>>(Xin, W1aT, nullptr, nullptr, b1ac, 1024, nullptr,
                                                          nullptr, W1bc, x2_);
    k_mlp2<<<32, 256, 0, stream>>>(x2_, b1bc, gfc, bfc, W2ac, b2ac, W2bc, b2bc, flags_, d_out);
}